// Round 18
// baseline (188.041 us; speedup 1.0000x reference)
//
#include <hip/hip_runtime.h>
#include <hip/hip_fp16.h>
#include <math.h>

#define N_NODES 50000
#define N_EDGES 1000000
#define F_IN 128
#define HID 16
#define N_CLS 40
#define HEADS 8
#define ET (N_EDGES + N_NODES)
#define XB ((N_NODES + 63) / 64)      // 782 xform blocks
#define HB ((ET + 255) / 256)         // 4103 hist blocks
#define NSCB ((N_NODES + 255) / 256)  // 196 scan blocks

typedef __attribute__((ext_vector_type(8))) _Float16 f16x8;
typedef __attribute__((ext_vector_type(4))) float f32x4;

// monotone float<->uint encoding for atomicMax on floats
__device__ __forceinline__ unsigned encf(float f) {
  unsigned b = __float_as_uint(f);
  return (b & 0x80000000u) ? ~b : (b | 0x80000000u);
}
__device__ __forceinline__ float decf(unsigned k) {
  unsigned b = (k & 0x80000000u) ? (k ^ 0x80000000u) : ~k;
  return __uint_as_float(b);
}

// ---------------- one-time W transpose to f16 [ch][k] ----------------

__global__ __launch_bounds__(256) void k_wprep(const float* __restrict__ W1,
                                               __half* __restrict__ wt16) {
  int i = blockIdx.x * 256 + threadIdx.x;  // 64 blocks x 256 = 16384
  int ch = i >> 7, k = i & 127;
  wt16[ch * 128 + k] = __float2half(W1[(size_t)k * 128 + ch]);
}

// ---------------- conv1 transform: f16 MFMA GEMM (+ hist blocks, as1-max) ----
// MFMA core identical to r15 (absmax-verified). Staging/epilogue fixed:
// W from pre-transposed wt16 via linear swizzled copy (conflict-free);
// h1 stored via LDS repack -> coalesced uint4 stores (ALL 1024 uint4 now).

__global__ __launch_bounds__(256) void k_xform1(
    const float* __restrict__ x, const __half* __restrict__ wt16,
    const float* __restrict__ att_s, const float* __restrict__ att_d,
    const int* __restrict__ ei, int* __restrict__ deg, int* __restrict__ epos,
    __half* __restrict__ h1, float* __restrict__ as1, float* __restrict__ ad1,
    unsigned* __restrict__ enc1) {
  if (blockIdx.x >= XB) {  // histogram blocks
    int i = (blockIdx.x - XB) * 256 + threadIdx.x;
    if (i < ET) {
      int dd = (i < N_EDGES) ? ei[N_EDGES + i] : (i - N_EDGES);
      epos[i] = atomicAdd(&deg[dd], 1);
    }
    return;
  }
  __shared__ __half xl[64 * 128];    // 16KB: x tile (swizzled), later h1 tile
  __shared__ __half wt[128 * 128];   // 32KB: W^T (swizzled)
  __shared__ unsigned encl[8];
  int t = threadIdx.x;
  if (t < 8) encl[t] = 0u;
  int base = blockIdx.x * 64;
  const float4* x4 = (const float4*)x;

  // stage x: f32 -> f16, swizzled rows (256B/node); conflict-free
#pragma unroll
  for (int u = 0; u < 8; u++) {
    int i = t + u * 256;
    int n = i >> 5, q = i & 31;
    int gn = base + n;
    float4 v = {0.f, 0.f, 0.f, 0.f};
    if (gn < N_NODES) v = x4[(size_t)gn * 32 + q];
    uint2 pk;
    __half2* ph = (__half2*)&pk;
    ph[0] = __floats2half2_rn(v.x, v.y);
    ph[1] = __floats2half2_rn(v.z, v.w);
    unsigned byte = (unsigned)(n * 256 + q * 8) ^ ((n & 7) << 4);
    *(uint2*)((char*)xl + byte) = pk;
  }
  // stage W^T: linear coalesced uint4 copy with row swizzle; conflict-free
  {
    const uint4* wt4 = (const uint4*)wt16;
#pragma unroll
    for (int u = 0; u < 8; u++) {
      int i = t + u * 256;              // 0..2047 uint4
      unsigned lin = (unsigned)i * 16;
      unsigned row = lin >> 8;          // ch
      unsigned byte = lin ^ ((row & 7) << 4);
      *(uint4*)((char*)wt + byte) = wt4[i];
    }
  }
  __syncthreads();

  int l = t & 63, wv = t >> 6;
  int lm = l & 15, lh = l >> 4;
  int n0 = wv * 16;
  int node = n0 + lm;
  bool wvalid = (base + n0) < N_NODES;  // 50000 % 16 == 0

  f32x4 acc[8];
#pragma unroll
  for (int f = 0; f < 8; f++) acc[f] = (f32x4){0.f, 0.f, 0.f, 0.f};

#pragma unroll
  for (int kb = 0; kb < 4; kb++) {
    int kbase = kb * 32 + lh * 8;
    unsigned ab = ((unsigned)(node * 256 + kbase * 2)) ^ ((node & 7) << 4);
    f16x8 af = *(const f16x8*)((const char*)xl + ab);
#pragma unroll
    for (int f = 0; f < 8; f++) {
      int ch = f * 16 + lm;
      unsigned bb = ((unsigned)(ch * 256 + kbase * 2)) ^ ((ch & 7) << 4);
      f16x8 bf = *(const f16x8*)((const char*)wt + bb);
      acc[f] = __builtin_amdgcn_mfma_f32_16x16x32_f16(af, bf, acc[f], 0, 0, 0);
    }
  }

  // epilogue part 1: per-head att dots (head == frag), as1/ad1, local max
  int nr_loc = n0 + lh * 4;
  int nr = base + nr_loc;
#pragma unroll
  for (int f = 0; f < 8; f++) {
    float asv = att_s[f * 16 + lm];
    float adv = att_d[f * 16 + lm];
    float ps0 = acc[f].x * asv, ps1 = acc[f].y * asv;
    float ps2 = acc[f].z * asv, ps3 = acc[f].w * asv;
    float pd0 = acc[f].x * adv, pd1 = acc[f].y * adv;
    float pd2 = acc[f].z * adv, pd3 = acc[f].w * adv;
#pragma unroll
    for (int off = 1; off <= 8; off <<= 1) {
      ps0 += __shfl_xor(ps0, off); ps1 += __shfl_xor(ps1, off);
      ps2 += __shfl_xor(ps2, off); ps3 += __shfl_xor(ps3, off);
      pd0 += __shfl_xor(pd0, off); pd1 += __shfl_xor(pd1, off);
      pd2 += __shfl_xor(pd2, off); pd3 += __shfl_xor(pd3, off);
    }
    if (wvalid && lm == 0) {
      as1[(nr + 0) * 8 + f] = ps0; ad1[(nr + 0) * 8 + f] = pd0;
      as1[(nr + 1) * 8 + f] = ps1; ad1[(nr + 1) * 8 + f] = pd1;
      as1[(nr + 2) * 8 + f] = ps2; ad1[(nr + 2) * 8 + f] = pd2;
      as1[(nr + 3) * 8 + f] = ps3; ad1[(nr + 3) * 8 + f] = pd3;
      float m = fmaxf(fmaxf(ps0, ps1), fmaxf(ps2, ps3));
      atomicMax(&encl[f], encf(m));
    }
  }

  // epilogue part 2: repack acc -> xl as linear h1 tile, coalesced store
  __syncthreads();  // all MFMA reads of xl complete
#pragma unroll
  for (int f = 0; f < 8; f++) {
    int cb = f * 16 + lm;
    xl[(nr_loc + 0) * 128 + cb] = __float2half(acc[f].x);
    xl[(nr_loc + 1) * 128 + cb] = __float2half(acc[f].y);
    xl[(nr_loc + 2) * 128 + cb] = __float2half(acc[f].z);
    xl[(nr_loc + 3) * 128 + cb] = __float2half(acc[f].w);
  }
  __syncthreads();
  {
    const uint4* src = (const uint4*)xl;
    uint4* dst = (uint4*)(h1 + (size_t)base * 128);
#pragma unroll
    for (int u = 0; u < 4; u++) {     // 1024 uint4 = full 64-node tile
      int i = t + u * 256;
      int nl = i >> 4;                // 16 uint4 per node
      if (base + nl < N_NODES) dst[i] = src[i];
    }
  }
  if (t < 8) atomicMax(&enc1[t], encl[t]);
}

// ---------------- 3-kernel coalesced exclusive scan of deg -> start ----------

__global__ __launch_bounds__(256) void k_scanA(const int* __restrict__ deg,
                                               int* __restrict__ bsum) {
  int i = blockIdx.x * 256 + threadIdx.x;
  int v = (i < N_NODES) ? deg[i] : 0;
#pragma unroll
  for (int off = 32; off; off >>= 1) v += __shfl_xor(v, off);
  __shared__ int ws[4];
  if ((threadIdx.x & 63) == 0) ws[threadIdx.x >> 6] = v;
  __syncthreads();
  if (threadIdx.x == 0) bsum[blockIdx.x] = ws[0] + ws[1] + ws[2] + ws[3];
}

__global__ __launch_bounds__(256) void k_scanB(const int* __restrict__ bsum,
                                               int* __restrict__ boff,
                                               int* __restrict__ start,
                                               const unsigned* __restrict__ enc1,
                                               float* __restrict__ fmax1) {
  __shared__ int s[256];
  int t = threadIdx.x;
  int v0 = (t < NSCB) ? bsum[t] : 0;
  s[t] = v0;
  __syncthreads();
  for (int off = 1; off < 256; off <<= 1) {
    int v = (t >= off) ? s[t - off] : 0;
    __syncthreads();
    s[t] += v;
    __syncthreads();
  }
  boff[t] = s[t] - v0;  // exclusive
  if (t == 0) start[N_NODES] = ET;
  if (t < 8) fmax1[t] = decf(enc1[t]);  // pre-decode as1 per-head max
}

__global__ __launch_bounds__(256) void k_scanC(const int* __restrict__ deg,
                                               const int* __restrict__ boff,
                                               int* __restrict__ start) {
  __shared__ int s[256];
  int t = threadIdx.x;
  int i = blockIdx.x * 256 + t;
  int v0 = (i < N_NODES) ? deg[i] : 0;
  s[t] = v0;
  __syncthreads();
  for (int off = 1; off < 256; off <<= 1) {
    int v = (t >= off) ? s[t - off] : 0;
    __syncthreads();
    s[t] += v;
    __syncthreads();
  }
  if (i < N_NODES) start[i] = boff[blockIdx.x] + s[t] - v0;
}

// atomic-free scatter: position precomputed by hist
__global__ void k_scatter(const int* __restrict__ ei, const int* __restrict__ start,
                          const int* __restrict__ epos, int* __restrict__ esrc) {
  int i = blockIdx.x * blockDim.x + threadIdx.x;
  if (i >= ET) return;
  int s, d;
  if (i < N_EDGES) { s = ei[i]; d = ei[N_EDGES + i]; }
  else { s = i - N_EDGES; d = s; }
  esrc[start[d] + epos[i]] = s;
}

// ---------------- conv1 aggregation + fused conv2 transform ----------------
// 16-lane groups: wave = 4 dst; lane = 8 channels (16B dwordx4 gathers).
// 8-deep gather unroll; de-aligned p_t group stride (656B) to stagger banks.

__global__ __launch_bounds__(256) void k_agg1(
    const __half* __restrict__ h1, const float* __restrict__ as1,
    const float* __restrict__ ad1, const int* __restrict__ start,
    const int* __restrict__ esrc, const float* __restrict__ b1,
    const float* __restrict__ W2, const float* __restrict__ att_s2,
    const float* __restrict__ att_d2, const float* __restrict__ fmax1,
    __half* __restrict__ h2, float* __restrict__ as2, float* __restrict__ ad2) {
  __shared__ __align__(16) __half2 p_t[4][4 * 164];  // [wave][g*164 + head*20 + e]
  __shared__ __align__(16) int s_off[4][4][20];      // [wave][g][16e+pad]
  __shared__ float w2s[16 * 40];
  int t = threadIdx.x;
  for (int i = t; i < 640; i += 256) w2s[i] = W2[i];
  __syncthreads();

  int wave = t >> 6, lane = t & 63;
  int g = lane >> 4, li = lane & 15;
  int d = blockIdx.x * 16 + wave * 4 + g;  // 3125*16 = 50000 exact
  int s0 = start[d];
  int deg = start[d + 1] - s0;

  int dm = deg;
  dm = max(dm, __shfl_xor(dm, 16));
  dm = max(dm, __shfl_xor(dm, 32));

  float4 av0 = *(const float4*)(ad1 + d * 8);
  float4 av1 = *(const float4*)(ad1 + d * 8 + 4);
  float ad_[8] = {av0.x, av0.y, av0.z, av0.w, av1.x, av1.y, av1.z, av1.w};
  float c_[8];
#pragma unroll
  for (int h = 0; h < 8; h++) {
    float e = fmax1[h] + ad_[h];
    c_[h] = e > 0.f ? e : 0.2f * e;
  }

  float den = 0.f;
  float accf[8];
#pragma unroll
  for (int k = 0; k < 8; k++) accf[k] = 0.f;

  int hsel = li >> 1;
  const char* h1l = (const char*)(h1 + li * 8);  // lane's 16B channel chunk
  __half2* ptw = &p_t[wave][g * 164];
  const int* so = &s_off[wave][g][0];

  for (int be = 0; be < dm; be += 16) {
    int cnt = deg - be;  // may be <= 0
    bool act = li < cnt;
    int s = 0;
    if (act) s = esrc[s0 + be + li];
    s_off[wave][g][li] = act ? (s << 8) : 0;
    float4 p0 = {0.f, 0.f, 0.f, 0.f}, p1 = {0.f, 0.f, 0.f, 0.f};
    if (act) {
      p0 = *(const float4*)(as1 + (size_t)s * 8);
      p1 = *(const float4*)(as1 + (size_t)s * 8 + 4);
    }
    float ev[8] = {p0.x, p0.y, p0.z, p0.w, p1.x, p1.y, p1.z, p1.w};
#pragma unroll
    for (int h = 0; h < 8; h++) {
      float v = ev[h] + ad_[h];
      v = v > 0.f ? v : 0.2f * v;
      float pv = act ? __expf(v - c_[h]) : 0.f;
      __half hp = __float2half(pv);
      ptw[h * 20 + li] = __half2{hp, hp};
    }
    asm volatile("s_waitcnt lgkmcnt(0)" ::: "memory");

    int cm = min(dm - be, 16);
    const __half2* pt = ptw + hsel * 20;
    __half2 a0 = __floats2half2_rn(0.f, 0.f);
    __half2 a1 = __floats2half2_rn(0.f, 0.f);
    __half2 a2 = __floats2half2_rn(0.f, 0.f);
    __half2 a3 = __floats2half2_rn(0.f, 0.f);
    for (int e = 0; e < cm; e += 8) {  // pad entries are (p=0, off=0): safe
      int4 s4 = *(const int4*)&so[e];
      int4 s8 = *(const int4*)&so[e + 4];
      uint4 pwA = *(const uint4*)&pt[e];
      uint4 pwB = *(const uint4*)&pt[e + 4];
      const __half2* ppA = (const __half2*)&pwA;
      const __half2* ppB = (const __half2*)&pwB;
      uint4 hA = *(const uint4*)(h1l + (unsigned)s4.x);
      uint4 hB = *(const uint4*)(h1l + (unsigned)s4.y);
      uint4 hC = *(const uint4*)(h1l + (unsigned)s4.z);
      uint4 hD = *(const uint4*)(h1l + (unsigned)s4.w);
      uint4 hE = *(const uint4*)(h1l + (unsigned)s8.x);
      uint4 hF = *(const uint4*)(h1l + (unsigned)s8.y);
      uint4 hG = *(const uint4*)(h1l + (unsigned)s8.z);
      uint4 hH = *(const uint4*)(h1l + (unsigned)s8.w);
      const __half2* vA = (const __half2*)&hA;
      const __half2* vB = (const __half2*)&hB;
      const __half2* vC = (const __half2*)&hC;
      const __half2* vD = (const __half2*)&hD;
      const __half2* vE = (const __half2*)&hE;
      const __half2* vF = (const __half2*)&hF;
      const __half2* vG = (const __half2*)&hG;
      const __half2* vH = (const __half2*)&hH;
      a0 = __hfma2(vA[0], ppA[0], a0); a1 = __hfma2(vA[1], ppA[0], a1);
      a2 = __hfma2(vA[2], ppA[0], a2); a3 = __hfma2(vA[3], ppA[0], a3);
      a0 = __hfma2(vB[0], ppA[1], a0); a1 = __hfma2(vB[1], ppA[1], a1);
      a2 = __hfma2(vB[2], ppA[1], a2); a3 = __hfma2(vB[3], ppA[1], a3);
      a0 = __hfma2(vC[0], ppA[2], a0); a1 = __hfma2(vC[1], ppA[2], a1);
      a2 = __hfma2(vC[2], ppA[2], a2); a3 = __hfma2(vC[3], ppA[2], a3);
      a0 = __hfma2(vD[0], ppA[3], a0); a1 = __hfma2(vD[1], ppA[3], a1);
      a2 = __hfma2(vD[2], ppA[3], a2); a3 = __hfma2(vD[3], ppA[3], a3);
      a0 = __hfma2(vE[0], ppB[0], a0); a1 = __hfma2(vE[1], ppB[0], a1);
      a2 = __hfma2(vE[2], ppB[0], a2); a3 = __hfma2(vE[3], ppB[0], a3);
      a0 = __hfma2(vF[0], ppB[1], a0); a1 = __hfma2(vF[1], ppB[1], a1);
      a2 = __hfma2(vF[2], ppB[1], a2); a3 = __hfma2(vF[3], ppB[1], a3);
      a0 = __hfma2(vG[0], ppB[2], a0); a1 = __hfma2(vG[1], ppB[2], a1);
      a2 = __hfma2(vG[2], ppB[2], a2); a3 = __hfma2(vG[3], ppB[2], a3);
      a0 = __hfma2(vH[0], ppB[3], a0); a1 = __hfma2(vH[1], ppB[3], a1);
      a2 = __hfma2(vH[2], ppB[3], a2); a3 = __hfma2(vH[3], ppB[3], a3);
      den += __low2float(ppA[0]) + __low2float(ppA[1]) +
             __low2float(ppA[2]) + __low2float(ppA[3]) +
             __low2float(ppB[0]) + __low2float(ppB[1]) +
             __low2float(ppB[2]) + __low2float(ppB[3]);
    }
    // promote chunk accumulators to fp32
    float2 f0 = __half22float2(a0), f1 = __half22float2(a1);
    float2 f2 = __half22float2(a2), f3 = __half22float2(a3);
    accf[0] += f0.x; accf[1] += f0.y; accf[2] += f1.x; accf[3] += f1.y;
    accf[4] += f2.x; accf[5] += f2.y; accf[6] += f3.x; accf[7] += f3.y;
    asm volatile("s_waitcnt lgkmcnt(0)" ::: "memory");
  }

  // normalize by own head's den, fold in 1/8 head-mean
  float sc = 0.125f / den;
#pragma unroll
  for (int k = 0; k < 8; k++) accf[k] *= sc;
  // sum over heads: xor 2,4,8 within the 16-lane group
#pragma unroll
  for (int off = 2; off <= 8; off <<= 1) {
#pragma unroll
    for (int k = 0; k < 8; k++) accf[k] += __shfl_xor(accf[k], off);
  }
  // lane holds mean for ch (li&1)*8 + k
  int jb = (li & 1) * 8;
  float4 b1a = *(const float4*)(b1 + jb);
  float4 b1b = *(const float4*)(b1 + jb + 4);
  float bv[8] = {b1a.x, b1a.y, b1a.z, b1a.w, b1b.x, b1b.y, b1b.z, b1b.w};
  float r[8];
#pragma unroll
  for (int k = 0; k < 8; k++) {
    float v = accf[k] + bv[k];
    r[k] = v > 0.f ? v : __expf(v) - 1.f;
  }
  float ro[8];
#pragma unroll
  for (int k = 0; k < 8; k++) ro[k] = __shfl_xor(r[k], 1);

  // conv2 transform: outputs j = li, li+16, li+32(li<8)
  float o0 = 0.f, o1 = 0.f, o2 = 0.f;
  bool has2 = li < 8;
#pragma unroll
  for (int k = 0; k < 16; k++) {
    float rk;
    if (k < 8) rk = (li & 1) ? ro[k] : r[k];
    else       rk = (li & 1) ? r[k - 8] : ro[k - 8];
    o0 = fmaf(rk, w2s[k * 40 + li], o0);
    o1 = fmaf(rk, w2s[k * 40 + li + 16], o1);
    if (has2) o2 = fmaf(rk, w2s[k * 40 + li + 32], o2);
  }
  __half* h2r = h2 + d * 40;
  h2r[li] = __float2half(o0);
  h2r[li + 16] = __float2half(o1);
  if (has2) h2r[li + 32] = __float2half(o2);

  float sv = o0 * att_s2[li] + o1 * att_s2[li + 16];
  float dv = o0 * att_d2[li] + o1 * att_d2[li + 16];
  if (has2) {
    sv = fmaf(o2, att_s2[li + 32], sv);
    dv = fmaf(o2, att_d2[li + 32], dv);
  }
#pragma unroll
  for (int off = 1; off <= 8; off <<= 1) {
    sv += __shfl_xor(sv, off);
    dv += __shfl_xor(dv, off);
  }
  if (li == 0) { as2[d] = sv; ad2[d] = dv; }
}

// ---------------- global max of as2 ----------------

__global__ __launch_bounds__(256) void k_maxas2(const float* __restrict__ as2,
                                                unsigned* __restrict__ enc) {
  int t = blockIdx.x * 256 + threadIdx.x;  // 64 blocks -> 16384 threads
  float mx = -1e30f;
  for (int r = t; r < N_NODES; r += 16384) mx = fmaxf(mx, as2[r]);
#pragma unroll
  for (int off = 32; off; off >>= 1) mx = fmaxf(mx, __shfl_xor(mx, off));
  if ((threadIdx.x & 63) == 0) atomicMax(enc, encf(mx));
}

// ---------------- conv2 aggregation + bias + log_softmax ----------------
// 60 lanes = 20 channel-pairs x 3 edge-slots; 2 slot-groups in flight.

__global__ __launch_bounds__(256) void k_agg2(
    const __half* __restrict__ h2, const float* __restrict__ as2,
    const float* __restrict__ ad2, const int* __restrict__ start,
    const int* __restrict__ esrc, const float* __restrict__ b2,
    const unsigned* __restrict__ as2maxEnc, float* __restrict__ out) {
  __shared__ __align__(16) float p_l[4][64];
  __shared__ __align__(16) int s_l[4][64];  // byte offsets (s*80)
  int wave = threadIdx.x >> 6, lane = threadIdx.x & 63;
  int d = blockIdx.x * 4 + wave;
  if (d >= N_NODES) return;
  int s0 = start[d];
  int deg = start[d + 1] - s0;
  float adv = ad2[d];
  float cm = decf(as2maxEnc[0]) + adv;
  cm = cm > 0.f ? cm : 0.2f * cm;

  int cp = lane % 20;        // channel pair (ch 2cp, 2cp+1)
  int es = lane / 20;        // edge slot 0..2 (lanes >= 60 idle in serial)
  const char* h2b = (const char*)h2 + cp * 4;

  float den = 0.f, acc0 = 0.f, acc1 = 0.f;
  for (int be = 0; be < deg; be += 64) {
    int cnt = min(64, deg - be);
    if (lane < cnt) {
      int s = esrc[s0 + be + lane];
      s_l[wave][lane] = s * 80;  // byte offset into h2 (40 halves)
      float e = as2[s] + adv;
      e = e > 0.f ? e : 0.2f * e;
      float p = __expf(e - cm);
      den += p;
      p_l[wave][lane] = p;
    }
    asm volatile("s_waitcnt lgkmcnt(0)" ::: "memory");
    if (es < 3) {
      int i = 0;
      for (; i + 5 < cnt; i += 6) {
        int eA = i + es, eB = i + 3 + es;
        int sbA = s_l[wave][eA], sbB = s_l[wave][eB];
        float pA = p_l[wave][eA], pB = p_l[wave][eB];
        __half2 hvA = *(const __half2*)(h2b + (unsigned)sbA);
        __half2 hvB = *(const __half2*)(h2b + (unsigned)sbB);
        acc0 = fmaf(__half2float(hvA.x), pA, acc0);
        acc1 = fmaf(__half2float(hvA.y), pA, acc1);
        acc0 = fmaf(__half2float(hvB.x), pB, acc0);
        acc1 = fmaf(__half2float(hvB.y), pB, acc1);
      }
      for (; i < cnt; i += 3) {
        int e = i + es;
        if (e < cnt) {
          int sb = s_l[wave][e];
          float p = p_l[wave][e];
          __half2 hv = *(const __half2*)(h2b + (unsigned)sb);
          acc0 = fmaf(__half2float(hv.x), p, acc0);
          acc1 = fmaf(__half2float(hv.y), p, acc1);
        }
      }
    }
    asm volatile("s_waitcnt lgkmcnt(0)" ::: "memory");
  }
#pragma unroll
  for (int off = 32; off; off >>= 1) den += __shfl_xor(den, off);
  float iv = 1.f / den;

  // combine 3 edge-slots: lanes 0..19 gather from +20, +40
  acc0 += __shfl(acc0, lane + 20) + __shfl(acc0, lane + 40);
  acc1 += __shfl(acc1, lane + 20) + __shfl(acc1, lane + 40);
  // distribute pairs to 40-lane layout: channel j from lane j>>1, comp j&1
  float va = __shfl(acc0, lane >> 1);
  float vb = __shfl(acc1, lane >> 1);
  float v = (lane & 1) ? vb : va;
  v = (lane < N_CLS) ? v * iv + b2[lane] : -1e30f;

  float mx = v;
#pragma unroll
  for (int off = 32; off; off >>= 1) mx = fmaxf(mx, __shfl_xor(mx, off));
  float ex = (lane < N_CLS) ? __expf(v - mx) : 0.f;
  float sm = ex;
#pragma unroll
  for (int off = 32; off; off >>= 1) sm += __shfl_xor(sm, off);
  float lse = logf(sm);
  if (lane < N_CLS) out[d * N_CLS + lane] = (v - mx) - lse;
}

// ---------------- host launcher ----------------

extern "C" void kernel_launch(void* const* d_in, const int* in_sizes, int n_in,
                              void* d_out, int out_size, void* d_ws, size_t ws_size,
                              hipStream_t stream) {
  const float* x    = (const float*)d_in[0];
  const int*   ei   = (const int*)d_in[1];
  const float* W1   = (const float*)d_in[2];
  const float* as1w = (const float*)d_in[3];
  const float* ad1w = (const float*)d_in[4];
  const float* b1   = (const float*)d_in[5];
  const float* W2   = (const float*)d_in[6];
  const float* as2w = (const float*)d_in[7];
  const float* ad2w = (const float*)d_in[8];
  const float* b2   = (const float*)d_in[9];
  float* out = (float*)d_out;

  char* ws = (char*)d_ws;
  size_t off = 0;
  auto alloc = [&](size_t bytes) -> void* {
    void* p = ws + off;
    off += (bytes + 255) & ~(size_t)255;
    return p;
  };
  __half* h1   = (__half*)alloc((size_t)N_NODES * 128 * 2);
  float* as1   = (float*)alloc((size_t)N_NODES * 8 * 4);
  float* ad1   = (float*)alloc((size_t)N_NODES * 8 * 4);
  __half* h2   = (__half*)alloc((size_t)N_NODES * 40 * 2);
  float* as2   = (float*)alloc((size_t)N_NODES * 4);
  float* ad2   = (float*)alloc((size_t)N_NODES * 4);
  __half* wt16 = (__half*)alloc((size_t)128 * 128 * 2);
  // contiguous zero region: deg | maxenc(16)
  size_t zbytes = (size_t)N_NODES * 4 + 256;
  int* deg     = (int*)alloc(zbytes);
  unsigned* maxenc = (unsigned*)(deg + N_NODES);  // [0..7]=as1 heads, [8]=as2
  int* start   = (int*)alloc((size_t)(N_NODES + 1) * 4);
  int* esrc    = (int*)alloc((size_t)ET * 4);
  int* epos    = (int*)alloc((size_t)ET * 4);
  int* bsum    = (int*)alloc((size_t)NSCB * 4);
  int* boff    = (int*)alloc(256 * 4);
  float* fmax1 = (float*)alloc(32);

  (void)hipMemsetAsync(deg, 0, zbytes, stream);

  k_wprep<<<64, 256, 0, stream>>>(W1, wt16);
  k_xform1<<<XB + HB, 256, 0, stream>>>(x, wt16, as1w, ad1w, ei, deg, epos,
                                        h1, as1, ad1, maxenc);
  k_scanA<<<NSCB, 256, 0, stream>>>(deg, bsum);
  k_scanB<<<1, 256, 0, stream>>>(bsum, boff, start, maxenc, fmax1);
  k_scanC<<<NSCB, 256, 0, stream>>>(deg, boff, start);
  k_scatter<<<HB, 256, 0, stream>>>(ei, start, epos, esrc);

  k_agg1<<<N_NODES / 16, 256, 0, stream>>>(h1, as1, ad1, start, esrc, b1,
                                           W2, as2w, ad2w, fmax1,
                                           h2, as2, ad2);
  k_maxas2<<<64, 256, 0, stream>>>(as2, maxenc + 8);
  k_agg2<<<(N_NODES + 3) / 4, 256, 0, stream>>>(h2, as2, ad2, start, esrc, b2,
                                                maxenc + 8, out);
}

// Round 19
// 157.964 us; speedup vs baseline: 1.1904x; 1.1904x over previous
//
#include <hip/hip_runtime.h>
#include <hip/hip_fp16.h>
#include <math.h>

#define N_NODES 50000
#define N_EDGES 1000000
#define F_IN 128
#define HID 16
#define N_CLS 40
#define HEADS 8
#define ET (N_EDGES + N_NODES)
#define XB ((N_NODES + 63) / 64)   // 782 xform blocks
#define NBK 196                    // coarse buckets (dst >> 8)
#define NSB 256                    // scatter blocks
#define ECH ((ET + NSB - 1) / NSB) // 4103 edges per scatter block

__device__ __forceinline__ void fma4(float4& acc, float s, const float4& v) {
  acc.x += s * v.x;
  acc.y += s * v.y;
  acc.z += s * v.z;
  acc.w += s * v.w;
}

__device__ __forceinline__ float dot4(float4 a, float4 b) {
  return a.x * b.x + a.y * b.y + a.z * b.z + a.w * b.w;
}

// monotone float<->uint encoding for atomicMax on floats
__device__ __forceinline__ unsigned encf(float f) {
  unsigned b = __float_as_uint(f);
  return (b & 0x80000000u) ? ~b : (b | 0x80000000u);
}
__device__ __forceinline__ float decf(unsigned k) {
  unsigned b = (k & 0x80000000u) ? (k ^ 0x80000000u) : ~k;
  return __uint_as_float(b);
}

// ---------------- conv1 transform: pure f32 k-blocked GEMM (r14 core) -------
// LDS 25.6KB -> 4 blocks/CU. Thread (tx,ty) owns channels [4tx..4tx+3] and
// [64+4tx..64+4tx+3] for nodes 4ty..4ty+3. Fused att dots + as1-max.

__global__ __launch_bounds__(256, 4) void k_xform1(
    const float* __restrict__ x, const float* __restrict__ W1,
    const float* __restrict__ att_s, const float* __restrict__ att_d,
    __half* __restrict__ h1, float* __restrict__ as1, float* __restrict__ ad1,
    unsigned* __restrict__ enc1) {
  __shared__ float4 xlds[64 * 9];   // [node][k-quad within phase], padded
  __shared__ float4 wlds[32 * 33];  // [k within phase][c-quad], padded
  __shared__ unsigned encl[8];
  int t = threadIdx.x;
  if (t < 8) encl[t] = 0u;
  int tx = t & 15, ty = t >> 4;
  int base = blockIdx.x * 64;
  const float4* x4 = (const float4*)x;
  const float4* W4 = (const float4*)W1;

  float4 accA[4], accB[4];
#pragma unroll
  for (int n = 0; n < 4; n++) {
    accA[n] = {0.f, 0.f, 0.f, 0.f};
    accB[n] = {0.f, 0.f, 0.f, 0.f};
  }
  int n0 = ty * 4;

  for (int kb = 0; kb < 4; kb++) {
    __syncthreads();
    {
      int i = t;
      int n = i >> 3, q = i & 7;
      int gn = base + n;
      float4 v = {0.f, 0.f, 0.f, 0.f};
      if (gn < N_NODES) v = x4[(size_t)gn * 32 + kb * 8 + q];
      xlds[n * 9 + q] = v;
      i += 256;
      n = i >> 3; q = i & 7;
      gn = base + n;
      float4 v2 = {0.f, 0.f, 0.f, 0.f};
      if (gn < N_NODES) v2 = x4[(size_t)gn * 32 + kb * 8 + q];
      xlds[n * 9 + q] = v2;
    }
#pragma unroll
    for (int u = 0; u < 4; u++) {
      int i = t + u * 256;
      int r = i >> 5, q = i & 31;
      wlds[r * 33 + q] = W4[(size_t)(kb * 32 + r) * 32 + q];
    }
    __syncthreads();
#pragma unroll
    for (int kk = 0; kk < 8; kk++) {
      float4 xv0 = xlds[(n0 + 0) * 9 + kk];
      float4 xv1 = xlds[(n0 + 1) * 9 + kk];
      float4 xv2 = xlds[(n0 + 2) * 9 + kk];
      float4 xv3 = xlds[(n0 + 3) * 9 + kk];
#pragma unroll
      for (int j = 0; j < 4; j++) {
        float4 wA = wlds[(kk * 4 + j) * 33 + tx];
        float4 wB = wlds[(kk * 4 + j) * 33 + tx + 16];
        float s0 = (j == 0) ? xv0.x : (j == 1) ? xv0.y : (j == 2) ? xv0.z : xv0.w;
        float s1 = (j == 0) ? xv1.x : (j == 1) ? xv1.y : (j == 2) ? xv1.z : xv1.w;
        float s2 = (j == 0) ? xv2.x : (j == 1) ? xv2.y : (j == 2) ? xv2.z : xv2.w;
        float s3 = (j == 0) ? xv3.x : (j == 1) ? xv3.y : (j == 2) ? xv3.z : xv3.w;
        fma4(accA[0], s0, wA); fma4(accB[0], s0, wB);
        fma4(accA[1], s1, wA); fma4(accB[1], s1, wB);
        fma4(accA[2], s2, wA); fma4(accB[2], s2, wB);
        fma4(accA[3], s3, wA); fma4(accB[3], s3, wB);
      }
    }
  }

  int c4 = tx * 4;
  float4 asA = *(const float4*)(att_s + c4);
  float4 asB = *(const float4*)(att_s + 64 + c4);
  float4 adA = *(const float4*)(att_d + c4);
  float4 adB = *(const float4*)(att_d + 64 + c4);
  float mxA = -1e30f, mxB = -1e30f;
#pragma unroll
  for (int n = 0; n < 4; n++) {
    int gn = base + n0 + n;
    float psA = dot4(accA[n], asA);
    float psB = dot4(accB[n], asB);
    float pdA = dot4(accA[n], adA);
    float pdB = dot4(accB[n], adB);
    psA += __shfl_xor(psA, 1); psA += __shfl_xor(psA, 2);
    psB += __shfl_xor(psB, 1); psB += __shfl_xor(psB, 2);
    pdA += __shfl_xor(pdA, 1); pdA += __shfl_xor(pdA, 2);
    pdB += __shfl_xor(pdB, 1); pdB += __shfl_xor(pdB, 2);
    if (gn < N_NODES) {
      uint2 pkA, pkB;
      __half2* phA = (__half2*)&pkA;
      __half2* phB = (__half2*)&pkB;
      phA[0] = __floats2half2_rn(accA[n].x, accA[n].y);
      phA[1] = __floats2half2_rn(accA[n].z, accA[n].w);
      phB[0] = __floats2half2_rn(accB[n].x, accB[n].y);
      phB[1] = __floats2half2_rn(accB[n].z, accB[n].w);
      *(uint2*)(h1 + (size_t)gn * 128 + c4) = pkA;
      *(uint2*)(h1 + (size_t)gn * 128 + 64 + c4) = pkB;
      mxA = fmaxf(mxA, psA);
      mxB = fmaxf(mxB, psB);
      if ((tx & 3) == 0) {
        as1[gn * 8 + (tx >> 2)] = psA;
        as1[gn * 8 + 4 + (tx >> 2)] = psB;
        ad1[gn * 8 + (tx >> 2)] = pdA;
        ad1[gn * 8 + 4 + (tx >> 2)] = pdB;
      }
    }
  }
  if ((tx & 3) == 0) {
    atomicMax(&encl[tx >> 2], encf(mxA));
    atomicMax(&encl[4 + (tx >> 2)], encf(mxB));
  }
  __syncthreads();
  if (t < 8) atomicMax(&enc1[t], encl[t]);
}

// ---------------- radix CSR build: no global atomics, coalesced I/O ---------
// Pass A: per-block LDS histogram over 196 coarse buckets (dst >> 8)

__global__ __launch_bounds__(256) void k_rxA(const int* __restrict__ ei,
                                             int* __restrict__ bcnt) {
  __shared__ int cnt[NBK];
  int t = threadIdx.x, blk = blockIdx.x;
  if (t < NBK) cnt[t] = 0;
  __syncthreads();
  int lo = blk * ECH + t;
  int hi = min((blk + 1) * ECH, ET);
  for (int i = lo; i < hi; i += 256) {
    int d = (i < N_EDGES) ? ei[N_EDGES + i] : (i - N_EDGES);
    atomicAdd(&cnt[d >> 8], 1);
  }
  __syncthreads();
  if (t < NBK) bcnt[t * NSB + blk] = cnt[t];
}

// Pass B: per-bucket exclusive prefix over the 256 scatter blocks

__global__ __launch_bounds__(256) void k_rxScanB(const int* __restrict__ bcnt,
                                                 int* __restrict__ boffs,
                                                 int* __restrict__ btot) {
  __shared__ int s[256];
  int b = blockIdx.x, t = threadIdx.x;
  int v0 = bcnt[b * NSB + t];
  s[t] = v0;
  __syncthreads();
  for (int off = 1; off < 256; off <<= 1) {
    int v = (t >= off) ? s[t - off] : 0;
    __syncthreads();
    s[t] += v;
    __syncthreads();
  }
  boffs[b * NSB + t] = s[t] - v0;
  if (t == 255) btot[b] = s[255];
}

// Pass C: scan bucket totals -> bucket starts (= CSR offset of node b*256);
// also decode as1 per-head max, write start[N_NODES].

__global__ __launch_bounds__(256) void k_rxTot(const int* __restrict__ btot,
                                               int* __restrict__ bstart,
                                               int* __restrict__ start,
                                               const unsigned* __restrict__ enc1,
                                               float* __restrict__ fmax1) {
  __shared__ int s[256];
  int t = threadIdx.x;
  int v0 = (t < NBK) ? btot[t] : 0;
  s[t] = v0;
  __syncthreads();
  for (int off = 1; off < 256; off <<= 1) {
    int v = (t >= off) ? s[t - off] : 0;
    __syncthreads();
    s[t] += v;
    __syncthreads();
  }
  if (t < NBK) bstart[t] = s[t] - v0;
  if (t == 0) start[N_NODES] = ET;
  if (t < 8) fmax1[t] = decf(enc1[t]);
}

// Pass D: scatter (s,d) pairs into bucket regions via LDS cursors

__global__ __launch_bounds__(256) void k_rxScat(const int* __restrict__ ei,
                                                const int* __restrict__ bstart,
                                                const int* __restrict__ boffs,
                                                int2* __restrict__ eb) {
  __shared__ int cur[NBK];
  int t = threadIdx.x, blk = blockIdx.x;
  if (t < NBK) cur[t] = bstart[t] + boffs[t * NSB + blk];
  __syncthreads();
  int lo = blk * ECH + t;
  int hi = min((blk + 1) * ECH, ET);
  for (int i = lo; i < hi; i += 256) {
    int s, d;
    if (i < N_EDGES) { s = ei[i]; d = ei[N_EDGES + i]; }
    else { s = i - N_EDGES; d = s; }
    int pos = atomicAdd(&cur[d >> 8], 1);
    eb[pos] = make_int2(s, d);
  }
}

// Pass E: per-bucket local CSR build, fully in LDS; coalesced global writes

__global__ __launch_bounds__(256) void k_rxB(const int2* __restrict__ eb,
                                             const int* __restrict__ bstart,
                                             int* __restrict__ start,
                                             int* __restrict__ esrc) {
  __shared__ int dcnt[256], lst[256], ssc[256];
  __shared__ int esl[8192];  // bucket cap (mean 5357, +39 sigma)
  int t = threadIdx.x, b = blockIdx.x;
  int nlo = b * 256;
  int nn = min(256, N_NODES - nlo);
  int e0 = bstart[b];
  int e1 = (b == NBK - 1) ? ET : bstart[b + 1];
  int cnt = e1 - e0;
  dcnt[t] = 0;
  __syncthreads();
  for (int e = t; e < cnt; e += 256) atomicAdd(&dcnt[eb[e0 + e].y & 255], 1);
  __syncthreads();
  int v0 = dcnt[t];
  ssc[t] = v0;
  __syncthreads();
  for (int off = 1; off < 256; off <<= 1) {
    int v = (t >= off) ? ssc[t - off] : 0;
    __syncthreads();
    ssc[t] += v;
    __syncthreads();
  }
  lst[t] = ssc[t] - v0;  // exclusive
  if (t < nn) start[nlo + t] = e0 + lst[t];
  dcnt[t] = lst[t];      // reuse as cursor
  __syncthreads();
  for (int e = t; e < cnt; e += 256) {
    int2 p = eb[e0 + e];
    int pos = atomicAdd(&dcnt[p.y & 255], 1);
    esl[pos] = p.x;
  }
  __syncthreads();
  for (int e = t; e < cnt; e += 256) esrc[e0 + e] = esl[e];
}

// ---------------- conv1 aggregation + fused conv2 transform ----------------
// 16-lane groups: wave = 4 dst; lane = 8 channels (16B dwordx4 gathers).
// 8-deep gather unroll; de-aligned p_t group stride (656B) to stagger banks.

__global__ __launch_bounds__(256) void k_agg1(
    const __half* __restrict__ h1, const float* __restrict__ as1,
    const float* __restrict__ ad1, const int* __restrict__ start,
    const int* __restrict__ esrc, const float* __restrict__ b1,
    const float* __restrict__ W2, const float* __restrict__ att_s2,
    const float* __restrict__ att_d2, const float* __restrict__ fmax1,
    __half* __restrict__ h2, float* __restrict__ as2, float* __restrict__ ad2) {
  __shared__ __align__(16) __half2 p_t[4][4 * 164];  // [wave][g*164 + head*20 + e]
  __shared__ __align__(16) int s_off[4][4][20];      // [wave][g][16e+pad]
  __shared__ float w2s[16 * 40];
  int t = threadIdx.x;
  for (int i = t; i < 640; i += 256) w2s[i] = W2[i];
  __syncthreads();

  int wave = t >> 6, lane = t & 63;
  int g = lane >> 4, li = lane & 15;
  int d = blockIdx.x * 16 + wave * 4 + g;  // 3125*16 = 50000 exact
  int s0 = start[d];
  int deg = start[d + 1] - s0;

  int dm = deg;
  dm = max(dm, __shfl_xor(dm, 16));
  dm = max(dm, __shfl_xor(dm, 32));

  float4 av0 = *(const float4*)(ad1 + d * 8);
  float4 av1 = *(const float4*)(ad1 + d * 8 + 4);
  float ad_[8] = {av0.x, av0.y, av0.z, av0.w, av1.x, av1.y, av1.z, av1.w};
  float c_[8];
#pragma unroll
  for (int h = 0; h < 8; h++) {
    float e = fmax1[h] + ad_[h];
    c_[h] = e > 0.f ? e : 0.2f * e;
  }

  float den = 0.f;
  float accf[8];
#pragma unroll
  for (int k = 0; k < 8; k++) accf[k] = 0.f;

  int hsel = li >> 1;
  const char* h1l = (const char*)(h1 + li * 8);  // lane's 16B channel chunk
  __half2* ptw = &p_t[wave][g * 164];
  const int* so = &s_off[wave][g][0];

  for (int be = 0; be < dm; be += 16) {
    int cnt = deg - be;  // may be <= 0
    bool act = li < cnt;
    int s = 0;
    if (act) s = esrc[s0 + be + li];
    s_off[wave][g][li] = act ? (s << 8) : 0;
    float4 p0 = {0.f, 0.f, 0.f, 0.f}, p1 = {0.f, 0.f, 0.f, 0.f};
    if (act) {
      p0 = *(const float4*)(as1 + (size_t)s * 8);
      p1 = *(const float4*)(as1 + (size_t)s * 8 + 4);
    }
    float ev[8] = {p0.x, p0.y, p0.z, p0.w, p1.x, p1.y, p1.z, p1.w};
#pragma unroll
    for (int h = 0; h < 8; h++) {
      float v = ev[h] + ad_[h];
      v = v > 0.f ? v : 0.2f * v;
      float pv = act ? __expf(v - c_[h]) : 0.f;
      __half hp = __float2half(pv);
      ptw[h * 20 + li] = __half2{hp, hp};
    }
    asm volatile("s_waitcnt lgkmcnt(0)" ::: "memory");

    int cm = min(dm - be, 16);
    const __half2* pt = ptw + hsel * 20;
    __half2 a0 = __floats2half2_rn(0.f, 0.f);
    __half2 a1 = __floats2half2_rn(0.f, 0.f);
    __half2 a2 = __floats2half2_rn(0.f, 0.f);
    __half2 a3 = __floats2half2_rn(0.f, 0.f);
    for (int e = 0; e < cm; e += 8) {  // pad entries are (p=0, off=0): safe
      int4 s4 = *(const int4*)&so[e];
      int4 s8 = *(const int4*)&so[e + 4];
      uint4 pwA = *(const uint4*)&pt[e];
      uint4 pwB = *(const uint4*)&pt[e + 4];
      const __half2* ppA = (const __half2*)&pwA;
      const __half2* ppB = (const __half2*)&pwB;
      uint4 hA = *(const uint4*)(h1l + (unsigned)s4.x);
      uint4 hB = *(const uint4*)(h1l + (unsigned)s4.y);
      uint4 hC = *(const uint4*)(h1l + (unsigned)s4.z);
      uint4 hD = *(const uint4*)(h1l + (unsigned)s4.w);
      uint4 hE = *(const uint4*)(h1l + (unsigned)s8.x);
      uint4 hF = *(const uint4*)(h1l + (unsigned)s8.y);
      uint4 hG = *(const uint4*)(h1l + (unsigned)s8.z);
      uint4 hH = *(const uint4*)(h1l + (unsigned)s8.w);
      const __half2* vA = (const __half2*)&hA;
      const __half2* vB = (const __half2*)&hB;
      const __half2* vC = (const __half2*)&hC;
      const __half2* vD = (const __half2*)&hD;
      const __half2* vE = (const __half2*)&hE;
      const __half2* vF = (const __half2*)&hF;
      const __half2* vG = (const __half2*)&hG;
      const __half2* vH = (const __half2*)&hH;
      a0 = __hfma2(vA[0], ppA[0], a0); a1 = __hfma2(vA[1], ppA[0], a1);
      a2 = __hfma2(vA[2], ppA[0], a2); a3 = __hfma2(vA[3], ppA[0], a3);
      a0 = __hfma2(vB[0], ppA[1], a0); a1 = __hfma2(vB[1], ppA[1], a1);
      a2 = __hfma2(vB[2], ppA[1], a2); a3 = __hfma2(vB[3], ppA[1], a3);
      a0 = __hfma2(vC[0], ppA[2], a0); a1 = __hfma2(vC[1], ppA[2], a1);
      a2 = __hfma2(vC[2], ppA[2], a2); a3 = __hfma2(vC[3], ppA[2], a3);
      a0 = __hfma2(vD[0], ppA[3], a0); a1 = __hfma2(vD[1], ppA[3], a1);
      a2 = __hfma2(vD[2], ppA[3], a2); a3 = __hfma2(vD[3], ppA[3], a3);
      a0 = __hfma2(vE[0], ppB[0], a0); a1 = __hfma2(vE[1], ppB[0], a1);
      a2 = __hfma2(vE[2], ppB[0], a2); a3 = __hfma2(vE[3], ppB[0], a3);
      a0 = __hfma2(vF[0], ppB[1], a0); a1 = __hfma2(vF[1], ppB[1], a1);
      a2 = __hfma2(vF[2], ppB[1], a2); a3 = __hfma2(vF[3], ppB[1], a3);
      a0 = __hfma2(vG[0], ppB[2], a0); a1 = __hfma2(vG[1], ppB[2], a1);
      a2 = __hfma2(vG[2], ppB[2], a2); a3 = __hfma2(vG[3], ppB[2], a3);
      a0 = __hfma2(vH[0], ppB[3], a0); a1 = __hfma2(vH[1], ppB[3], a1);
      a2 = __hfma2(vH[2], ppB[3], a2); a3 = __hfma2(vH[3], ppB[3], a3);
      den += __low2float(ppA[0]) + __low2float(ppA[1]) +
             __low2float(ppA[2]) + __low2float(ppA[3]) +
             __low2float(ppB[0]) + __low2float(ppB[1]) +
             __low2float(ppB[2]) + __low2float(ppB[3]);
    }
    // promote chunk accumulators to fp32
    float2 f0 = __half22float2(a0), f1 = __half22float2(a1);
    float2 f2 = __half22float2(a2), f3 = __half22float2(a3);
    accf[0] += f0.x; accf[1] += f0.y; accf[2] += f1.x; accf[3] += f1.y;
    accf[4] += f2.x; accf[5] += f2.y; accf[6] += f3.x; accf[7] += f3.y;
    asm volatile("s_waitcnt lgkmcnt(0)" ::: "memory");
  }

  // normalize by own head's den, fold in 1/8 head-mean
  float sc = 0.125f / den;
#pragma unroll
  for (int k = 0; k < 8; k++) accf[k] *= sc;
  // sum over heads: xor 2,4,8 within the 16-lane group
#pragma unroll
  for (int off = 2; off <= 8; off <<= 1) {
#pragma unroll
    for (int k = 0; k < 8; k++) accf[k] += __shfl_xor(accf[k], off);
  }
  // lane holds mean for ch (li&1)*8 + k
  int jb = (li & 1) * 8;
  float4 b1a = *(const float4*)(b1 + jb);
  float4 b1b = *(const float4*)(b1 + jb + 4);
  float bv[8] = {b1a.x, b1a.y, b1a.z, b1a.w, b1b.x, b1b.y, b1b.z, b1b.w};
  float r[8];
#pragma unroll
  for (int k = 0; k < 8; k++) {
    float v = accf[k] + bv[k];
    r[k] = v > 0.f ? v : __expf(v) - 1.f;
  }
  float ro[8];
#pragma unroll
  for (int k = 0; k < 8; k++) ro[k] = __shfl_xor(r[k], 1);

  // conv2 transform: outputs j = li, li+16, li+32(li<8)
  float o0 = 0.f, o1 = 0.f, o2 = 0.f;
  bool has2 = li < 8;
#pragma unroll
  for (int k = 0; k < 16; k++) {
    float rk;
    if (k < 8) rk = (li & 1) ? ro[k] : r[k];
    else       rk = (li & 1) ? r[k - 8] : ro[k - 8];
    o0 = fmaf(rk, w2s[k * 40 + li], o0);
    o1 = fmaf(rk, w2s[k * 40 + li + 16], o1);
    if (has2) o2 = fmaf(rk, w2s[k * 40 + li + 32], o2);
  }
  __half* h2r = h2 + d * 40;
  h2r[li] = __float2half(o0);
  h2r[li + 16] = __float2half(o1);
  if (has2) h2r[li + 32] = __float2half(o2);

  float sv = o0 * att_s2[li] + o1 * att_s2[li + 16];
  float dv = o0 * att_d2[li] + o1 * att_d2[li + 16];
  if (has2) {
    sv = fmaf(o2, att_s2[li + 32], sv);
    dv = fmaf(o2, att_d2[li + 32], dv);
  }
#pragma unroll
  for (int off = 1; off <= 8; off <<= 1) {
    sv += __shfl_xor(sv, off);
    dv += __shfl_xor(dv, off);
  }
  if (li == 0) { as2[d] = sv; ad2[d] = dv; }
}

// ---------------- global max of as2 ----------------

__global__ __launch_bounds__(256) void k_maxas2(const float* __restrict__ as2,
                                                unsigned* __restrict__ enc) {
  int t = blockIdx.x * 256 + threadIdx.x;  // 64 blocks -> 16384 threads
  float mx = -1e30f;
  for (int r = t; r < N_NODES; r += 16384) mx = fmaxf(mx, as2[r]);
#pragma unroll
  for (int off = 32; off; off >>= 1) mx = fmaxf(mx, __shfl_xor(mx, off));
  if ((threadIdx.x & 63) == 0) atomicMax(enc, encf(mx));
}

// ---------------- conv2 aggregation + bias + log_softmax ----------------
// 60 lanes = 20 channel-pairs x 3 edge-slots; 2 slot-groups in flight.

__global__ __launch_bounds__(256) void k_agg2(
    const __half* __restrict__ h2, const float* __restrict__ as2,
    const float* __restrict__ ad2, const int* __restrict__ start,
    const int* __restrict__ esrc, const float* __restrict__ b2,
    const unsigned* __restrict__ as2maxEnc, float* __restrict__ out) {
  __shared__ __align__(16) float p_l[4][64];
  __shared__ __align__(16) int s_l[4][64];  // byte offsets (s*80)
  int wave = threadIdx.x >> 6, lane = threadIdx.x & 63;
  int d = blockIdx.x * 4 + wave;
  if (d >= N_NODES) return;
  int s0 = start[d];
  int deg = start[d + 1] - s0;
  float adv = ad2[d];
  float cm = decf(as2maxEnc[0]) + adv;
  cm = cm > 0.f ? cm : 0.2f * cm;

  int cp = lane % 20;        // channel pair (ch 2cp, 2cp+1)
  int es = lane / 20;        // edge slot 0..2 (lanes >= 60 idle in serial)
  const char* h2b = (const char*)h2 + cp * 4;

  float den = 0.f, acc0 = 0.f, acc1 = 0.f;
  for (int be = 0; be < deg; be += 64) {
    int cnt = min(64, deg - be);
    if (lane < cnt) {
      int s = esrc[s0 + be + lane];
      s_l[wave][lane] = s * 80;  // byte offset into h2 (40 halves)
      float e = as2[s] + adv;
      e = e > 0.f ? e : 0.2f * e;
      float p = __expf(e - cm);
      den += p;
      p_l[wave][lane] = p;
    }
    asm volatile("s_waitcnt lgkmcnt(0)" ::: "memory");
    if (es < 3) {
      int i = 0;
      for (; i + 5 < cnt; i += 6) {
        int eA = i + es, eB = i + 3 + es;
        int sbA = s_l[wave][eA], sbB = s_l[wave][eB];
        float pA = p_l[wave][eA], pB = p_l[wave][eB];
        __half2 hvA = *(const __half2*)(h2b + (unsigned)sbA);
        __half2 hvB = *(const __half2*)(h2b + (unsigned)sbB);
        acc0 = fmaf(__half2float(hvA.x), pA, acc0);
        acc1 = fmaf(__half2float(hvA.y), pA, acc1);
        acc0 = fmaf(__half2float(hvB.x), pB, acc0);
        acc1 = fmaf(__half2float(hvB.y), pB, acc1);
      }
      for (; i < cnt; i += 3) {
        int e = i + es;
        if (e < cnt) {
          int sb = s_l[wave][e];
          float p = p_l[wave][e];
          __half2 hv = *(const __half2*)(h2b + (unsigned)sb);
          acc0 = fmaf(__half2float(hv.x), p, acc0);
          acc1 = fmaf(__half2float(hv.y), p, acc1);
        }
      }
    }
    asm volatile("s_waitcnt lgkmcnt(0)" ::: "memory");
  }
#pragma unroll
  for (int off = 32; off; off >>= 1) den += __shfl_xor(den, off);
  float iv = 1.f / den;

  // combine 3 edge-slots: lanes 0..19 gather from +20, +40
  acc0 += __shfl(acc0, lane + 20) + __shfl(acc0, lane + 40);
  acc1 += __shfl(acc1, lane + 20) + __shfl(acc1, lane + 40);
  // distribute pairs to 40-lane layout: channel j from lane j>>1, comp j&1
  float va = __shfl(acc0, lane >> 1);
  float vb = __shfl(acc1, lane >> 1);
  float v = (lane & 1) ? vb : va;
  v = (lane < N_CLS) ? v * iv + b2[lane] : -1e30f;

  float mx = v;
#pragma unroll
  for (int off = 32; off; off >>= 1) mx = fmaxf(mx, __shfl_xor(mx, off));
  float ex = (lane < N_CLS) ? __expf(v - mx) : 0.f;
  float sm = ex;
#pragma unroll
  for (int off = 32; off; off >>= 1) sm += __shfl_xor(sm, off);
  float lse = logf(sm);
  if (lane < N_CLS) out[d * N_CLS + lane] = (v - mx) - lse;
}

// ---------------- host launcher ----------------

extern "C" void kernel_launch(void* const* d_in, const int* in_sizes, int n_in,
                              void* d_out, int out_size, void* d_ws, size_t ws_size,
                              hipStream_t stream) {
  const float* x    = (const float*)d_in[0];
  const int*   ei   = (const int*)d_in[1];
  const float* W1   = (const float*)d_in[2];
  const float* as1w = (const float*)d_in[3];
  const float* ad1w = (const float*)d_in[4];
  const float* b1   = (const float*)d_in[5];
  const float* W2   = (const float*)d_in[6];
  const float* as2w = (const float*)d_in[7];
  const float* ad2w = (const float*)d_in[8];
  const float* b2   = (const float*)d_in[9];
  float* out = (float*)d_out;

  char* ws = (char*)d_ws;
  size_t off = 0;
  auto alloc = [&](size_t bytes) -> void* {
    void* p = ws + off;
    off += (bytes + 255) & ~(size_t)255;
    return p;
  };
  __half* h1   = (__half*)alloc((size_t)N_NODES * 128 * 2);
  float* as1   = (float*)alloc((size_t)N_NODES * 8 * 4);
  float* ad1   = (float*)alloc((size_t)N_NODES * 8 * 4);
  __half* h2   = (__half*)alloc((size_t)N_NODES * 40 * 2);
  float* as2   = (float*)alloc((size_t)N_NODES * 4);
  float* ad2   = (float*)alloc((size_t)N_NODES * 4);
  unsigned* maxenc = (unsigned*)alloc(256);  // [0..7]=as1 heads, [8]=as2
  int* start   = (int*)alloc((size_t)(N_NODES + 1) * 4);
  int* esrc    = (int*)alloc((size_t)ET * 4);
  int2* eb     = (int2*)alloc((size_t)ET * 8);
  int* bcnt    = (int*)alloc((size_t)NBK * NSB * 4);
  int* boffs   = (int*)alloc((size_t)NBK * NSB * 4);
  int* btot    = (int*)alloc((size_t)NBK * 4);
  int* bstart  = (int*)alloc((size_t)NBK * 4);
  float* fmax1 = (float*)alloc(32);

  (void)hipMemsetAsync(maxenc, 0, 256, stream);

  k_xform1<<<XB, 256, 0, stream>>>(x, W1, as1w, ad1w, h1, as1, ad1, maxenc);
  k_rxA<<<NSB, 256, 0, stream>>>(ei, bcnt);
  k_rxScanB<<<NBK, 256, 0, stream>>>(bcnt, boffs, btot);
  k_rxTot<<<1, 256, 0, stream>>>(btot, bstart, start, maxenc, fmax1);
  k_rxScat<<<NSB, 256, 0, stream>>>(ei, bstart, boffs, eb);
  k_rxB<<<NBK, 256, 0, stream>>>(eb, bstart, start, esrc);

  k_agg1<<<N_NODES / 16, 256, 0, stream>>>(h1, as1, ad1, start, esrc, b1,
                                           W2, as2w, ad2w, fmax1,
                                           h2, as2, ad2);
  k_maxas2<<<64, 256, 0, stream>>>(as2, maxenc + 8);
  k_agg2<<<(N_NODES + 3) / 4, 256, 0, stream>>>(h2, as2, ad2, start, esrc, b2,
                                                maxenc + 8, out);
}

// Round 20
// 156.740 us; speedup vs baseline: 1.1997x; 1.0078x over previous
//
#include <hip/hip_runtime.h>
#include <hip/hip_fp16.h>
#include <math.h>

#define N_NODES 50000
#define N_EDGES 1000000
#define F_IN 128
#define HID 16
#define N_CLS 40
#define HEADS 8
#define ET (N_EDGES + N_NODES)
#define XB ((N_NODES + 63) / 64)   // 782 xform blocks
#define NBK 196                    // coarse buckets (dst >> 8)
#define NSB 256                    // scatter blocks
#define ECH ((ET + NSB - 1) / NSB) // 4103 edges per scatter block

__device__ __forceinline__ void fma4(float4& acc, float s, const float4& v) {
  acc.x += s * v.x;
  acc.y += s * v.y;
  acc.z += s * v.z;
  acc.w += s * v.w;
}

__device__ __forceinline__ float dot4(float4 a, float4 b) {
  return a.x * b.x + a.y * b.y + a.z * b.z + a.w * b.w;
}

// monotone float<->uint encoding for atomicMax on floats
__device__ __forceinline__ unsigned encf(float f) {
  unsigned b = __float_as_uint(f);
  return (b & 0x80000000u) ? ~b : (b | 0x80000000u);
}
__device__ __forceinline__ float decf(unsigned k) {
  unsigned b = (k & 0x80000000u) ? (k ^ 0x80000000u) : ~k;
  return __uint_as_float(b);
}

// ---------------- conv1 transform: pure f32 k-blocked GEMM (r14 core) -------

__global__ __launch_bounds__(256, 4) void k_xform1(
    const float* __restrict__ x, const float* __restrict__ W1,
    const float* __restrict__ att_s, const float* __restrict__ att_d,
    __half* __restrict__ h1, float* __restrict__ as1, float* __restrict__ ad1,
    unsigned* __restrict__ enc1) {
  __shared__ float4 xlds[64 * 9];   // [node][k-quad within phase], padded
  __shared__ float4 wlds[32 * 33];  // [k within phase][c-quad], padded
  __shared__ unsigned encl[8];
  int t = threadIdx.x;
  if (t < 8) encl[t] = 0u;
  int tx = t & 15, ty = t >> 4;
  int base = blockIdx.x * 64;
  const float4* x4 = (const float4*)x;
  const float4* W4 = (const float4*)W1;

  float4 accA[4], accB[4];
#pragma unroll
  for (int n = 0; n < 4; n++) {
    accA[n] = {0.f, 0.f, 0.f, 0.f};
    accB[n] = {0.f, 0.f, 0.f, 0.f};
  }
  int n0 = ty * 4;

  for (int kb = 0; kb < 4; kb++) {
    __syncthreads();
    {
      int i = t;
      int n = i >> 3, q = i & 7;
      int gn = base + n;
      float4 v = {0.f, 0.f, 0.f, 0.f};
      if (gn < N_NODES) v = x4[(size_t)gn * 32 + kb * 8 + q];
      xlds[n * 9 + q] = v;
      i += 256;
      n = i >> 3; q = i & 7;
      gn = base + n;
      float4 v2 = {0.f, 0.f, 0.f, 0.f};
      if (gn < N_NODES) v2 = x4[(size_t)gn * 32 + kb * 8 + q];
      xlds[n * 9 + q] = v2;
    }
#pragma unroll
    for (int u = 0; u < 4; u++) {
      int i = t + u * 256;
      int r = i >> 5, q = i & 31;
      wlds[r * 33 + q] = W4[(size_t)(kb * 32 + r) * 32 + q];
    }
    __syncthreads();
#pragma unroll
    for (int kk = 0; kk < 8; kk++) {
      float4 xv0 = xlds[(n0 + 0) * 9 + kk];
      float4 xv1 = xlds[(n0 + 1) * 9 + kk];
      float4 xv2 = xlds[(n0 + 2) * 9 + kk];
      float4 xv3 = xlds[(n0 + 3) * 9 + kk];
#pragma unroll
      for (int j = 0; j < 4; j++) {
        float4 wA = wlds[(kk * 4 + j) * 33 + tx];
        float4 wB = wlds[(kk * 4 + j) * 33 + tx + 16];
        float s0 = (j == 0) ? xv0.x : (j == 1) ? xv0.y : (j == 2) ? xv0.z : xv0.w;
        float s1 = (j == 0) ? xv1.x : (j == 1) ? xv1.y : (j == 2) ? xv1.z : xv1.w;
        float s2 = (j == 0) ? xv2.x : (j == 1) ? xv2.y : (j == 2) ? xv2.z : xv2.w;
        float s3 = (j == 0) ? xv3.x : (j == 1) ? xv3.y : (j == 2) ? xv3.z : xv3.w;
        fma4(accA[0], s0, wA); fma4(accB[0], s0, wB);
        fma4(accA[1], s1, wA); fma4(accB[1], s1, wB);
        fma4(accA[2], s2, wA); fma4(accB[2], s2, wB);
        fma4(accA[3], s3, wA); fma4(accB[3], s3, wB);
      }
    }
  }

  int c4 = tx * 4;
  float4 asA = *(const float4*)(att_s + c4);
  float4 asB = *(const float4*)(att_s + 64 + c4);
  float4 adA = *(const float4*)(att_d + c4);
  float4 adB = *(const float4*)(att_d + 64 + c4);
  float mxA = -1e30f, mxB = -1e30f;
#pragma unroll
  for (int n = 0; n < 4; n++) {
    int gn = base + n0 + n;
    float psA = dot4(accA[n], asA);
    float psB = dot4(accB[n], asB);
    float pdA = dot4(accA[n], adA);
    float pdB = dot4(accB[n], adB);
    psA += __shfl_xor(psA, 1); psA += __shfl_xor(psA, 2);
    psB += __shfl_xor(psB, 1); psB += __shfl_xor(psB, 2);
    pdA += __shfl_xor(pdA, 1); pdA += __shfl_xor(pdA, 2);
    pdB += __shfl_xor(pdB, 1); pdB += __shfl_xor(pdB, 2);
    if (gn < N_NODES) {
      uint2 pkA, pkB;
      __half2* phA = (__half2*)&pkA;
      __half2* phB = (__half2*)&pkB;
      phA[0] = __floats2half2_rn(accA[n].x, accA[n].y);
      phA[1] = __floats2half2_rn(accA[n].z, accA[n].w);
      phB[0] = __floats2half2_rn(accB[n].x, accB[n].y);
      phB[1] = __floats2half2_rn(accB[n].z, accB[n].w);
      *(uint2*)(h1 + (size_t)gn * 128 + c4) = pkA;
      *(uint2*)(h1 + (size_t)gn * 128 + 64 + c4) = pkB;
      mxA = fmaxf(mxA, psA);
      mxB = fmaxf(mxB, psB);
      if ((tx & 3) == 0) {
        as1[gn * 8 + (tx >> 2)] = psA;
        as1[gn * 8 + 4 + (tx >> 2)] = psB;
        ad1[gn * 8 + (tx >> 2)] = pdA;
        ad1[gn * 8 + 4 + (tx >> 2)] = pdB;
      }
    }
  }
  if ((tx & 3) == 0) {
    atomicMax(&encl[tx >> 2], encf(mxA));
    atomicMax(&encl[4 + (tx >> 2)], encf(mxB));
  }
  __syncthreads();
  if (t < 8) atomicMax(&enc1[t], encl[t]);
}

// ---------------- radix CSR build (round-19, measured-good) ----------------

__global__ __launch_bounds__(256) void k_rxA(const int* __restrict__ ei,
                                             int* __restrict__ bcnt) {
  __shared__ int cnt[NBK];
  int t = threadIdx.x, blk = blockIdx.x;
  if (t < NBK) cnt[t] = 0;
  __syncthreads();
  int lo = blk * ECH + t;
  int hi = min((blk + 1) * ECH, ET);
  for (int i = lo; i < hi; i += 256) {
    int d = (i < N_EDGES) ? ei[N_EDGES + i] : (i - N_EDGES);
    atomicAdd(&cnt[d >> 8], 1);
  }
  __syncthreads();
  if (t < NBK) bcnt[t * NSB + blk] = cnt[t];
}

__global__ __launch_bounds__(256) void k_rxScanB(const int* __restrict__ bcnt,
                                                 int* __restrict__ boffs,
                                                 int* __restrict__ btot) {
  __shared__ int s[256];
  int b = blockIdx.x, t = threadIdx.x;
  int v0 = bcnt[b * NSB + t];
  s[t] = v0;
  __syncthreads();
  for (int off = 1; off < 256; off <<= 1) {
    int v = (t >= off) ? s[t - off] : 0;
    __syncthreads();
    s[t] += v;
    __syncthreads();
  }
  boffs[b * NSB + t] = s[t] - v0;
  if (t == 255) btot[b] = s[255];
}

// bucket-total scan + fmax decode + va/vd = W2^T-projected att vectors

__global__ __launch_bounds__(256) void k_rxTot(const int* __restrict__ btot,
                                               int* __restrict__ bstart,
                                               int* __restrict__ start,
                                               const unsigned* __restrict__ enc1,
                                               float* __restrict__ fmax1,
                                               const float* __restrict__ W2,
                                               const float* __restrict__ att_s2,
                                               const float* __restrict__ att_d2,
                                               float* __restrict__ va,
                                               float* __restrict__ vd) {
  __shared__ int s[256];
  int t = threadIdx.x;
  int v0 = (t < NBK) ? btot[t] : 0;
  s[t] = v0;
  __syncthreads();
  for (int off = 1; off < 256; off <<= 1) {
    int v = (t >= off) ? s[t - off] : 0;
    __syncthreads();
    s[t] += v;
    __syncthreads();
  }
  if (t < NBK) bstart[t] = s[t] - v0;
  if (t == 0) start[N_NODES] = ET;
  if (t < 8) fmax1[t] = decf(enc1[t]);
  if (t < 16) {
    float a = 0.f, dd = 0.f;
    for (int j = 0; j < N_CLS; j++) {
      float w = W2[t * N_CLS + j];
      a = fmaf(w, att_s2[j], a);
      dd = fmaf(w, att_d2[j], dd);
    }
    va[t] = a;
    vd[t] = dd;
  }
}

__global__ __launch_bounds__(256) void k_rxScat(const int* __restrict__ ei,
                                                const int* __restrict__ bstart,
                                                const int* __restrict__ boffs,
                                                int2* __restrict__ eb) {
  __shared__ int cur[NBK];
  int t = threadIdx.x, blk = blockIdx.x;
  if (t < NBK) cur[t] = bstart[t] + boffs[t * NSB + blk];
  __syncthreads();
  int lo = blk * ECH + t;
  int hi = min((blk + 1) * ECH, ET);
  for (int i = lo; i < hi; i += 256) {
    int s, d;
    if (i < N_EDGES) { s = ei[i]; d = ei[N_EDGES + i]; }
    else { s = i - N_EDGES; d = s; }
    int pos = atomicAdd(&cur[d >> 8], 1);
    eb[pos] = make_int2(s, d);
  }
}

__global__ __launch_bounds__(256) void k_rxB(const int2* __restrict__ eb,
                                             const int* __restrict__ bstart,
                                             int* __restrict__ start,
                                             int* __restrict__ esrc) {
  __shared__ int dcnt[256], lst[256], ssc[256];
  __shared__ int esl[8192];  // bucket cap (mean 5357, +39 sigma)
  int t = threadIdx.x, b = blockIdx.x;
  int nlo = b * 256;
  int nn = min(256, N_NODES - nlo);
  int e0 = bstart[b];
  int e1 = (b == NBK - 1) ? ET : bstart[b + 1];
  int cnt = e1 - e0;
  dcnt[t] = 0;
  __syncthreads();
  for (int e = t; e < cnt; e += 256) atomicAdd(&dcnt[eb[e0 + e].y & 255], 1);
  __syncthreads();
  int v0 = dcnt[t];
  ssc[t] = v0;
  __syncthreads();
  for (int off = 1; off < 256; off <<= 1) {
    int v = (t >= off) ? ssc[t - off] : 0;
    __syncthreads();
    ssc[t] += v;
    __syncthreads();
  }
  lst[t] = ssc[t] - v0;  // exclusive
  if (t < nn) start[nlo + t] = e0 + lst[t];
  dcnt[t] = lst[t];      // reuse as cursor
  __syncthreads();
  for (int e = t; e < cnt; e += 256) {
    int2 p = eb[e0 + e];
    int pos = atomicAdd(&dcnt[p.y & 255], 1);
    esl[pos] = p.x;
  }
  __syncthreads();
  for (int e = t; e < cnt; e += 256) esrc[e0 + e] = esl[e];
}

// ---------------- conv1 aggregation (h2 eliminated by linearity) -----------
// Outputs h1out[N,16] f16 + as2 = h1out.va, ad2 = h1out.vd.

__global__ __launch_bounds__(256) void k_agg1(
    const __half* __restrict__ h1, const float* __restrict__ as1,
    const float* __restrict__ ad1, const int* __restrict__ start,
    const int* __restrict__ esrc, const float* __restrict__ b1,
    const float* __restrict__ va, const float* __restrict__ vd,
    const float* __restrict__ fmax1,
    __half* __restrict__ h1o, float* __restrict__ as2, float* __restrict__ ad2) {
  __shared__ __align__(16) __half2 p_t[4][4 * 164];  // [wave][g*164 + head*20 + e]
  __shared__ __align__(16) int s_off[4][4][20];      // [wave][g][16e+pad]
  int t = threadIdx.x;

  int wave = t >> 6, lane = t & 63;
  int g = lane >> 4, li = lane & 15;
  int d = blockIdx.x * 16 + wave * 4 + g;  // 3125*16 = 50000 exact
  int s0 = start[d];
  int deg = start[d + 1] - s0;

  int dm = deg;
  dm = max(dm, __shfl_xor(dm, 16));
  dm = max(dm, __shfl_xor(dm, 32));

  float4 av0 = *(const float4*)(ad1 + d * 8);
  float4 av1 = *(const float4*)(ad1 + d * 8 + 4);
  float ad_[8] = {av0.x, av0.y, av0.z, av0.w, av1.x, av1.y, av1.z, av1.w};
  float c_[8];
#pragma unroll
  for (int h = 0; h < 8; h++) {
    float e = fmax1[h] + ad_[h];
    c_[h] = e > 0.f ? e : 0.2f * e;
  }

  float den = 0.f;
  float accf[8];
#pragma unroll
  for (int k = 0; k < 8; k++) accf[k] = 0.f;

  int hsel = li >> 1;
  const char* h1l = (const char*)(h1 + li * 8);  // lane's 16B channel chunk
  __half2* ptw = &p_t[wave][g * 164];
  const int* so = &s_off[wave][g][0];

  for (int be = 0; be < dm; be += 16) {
    int cnt = deg - be;  // may be <= 0
    bool act = li < cnt;
    int s = 0;
    if (act) s = esrc[s0 + be + li];
    s_off[wave][g][li] = act ? (s << 8) : 0;
    float4 p0 = {0.f, 0.f, 0.f, 0.f}, p1 = {0.f, 0.f, 0.f, 0.f};
    if (act) {
      p0 = *(const float4*)(as1 + (size_t)s * 8);
      p1 = *(const float4*)(as1 + (size_t)s * 8 + 4);
    }
    float ev[8] = {p0.x, p0.y, p0.z, p0.w, p1.x, p1.y, p1.z, p1.w};
#pragma unroll
    for (int h = 0; h < 8; h++) {
      float v = ev[h] + ad_[h];
      v = v > 0.f ? v : 0.2f * v;
      float pv = act ? __expf(v - c_[h]) : 0.f;
      __half hp = __float2half(pv);
      ptw[h * 20 + li] = __half2{hp, hp};
    }
    asm volatile("s_waitcnt lgkmcnt(0)" ::: "memory");

    int cm = min(dm - be, 16);
    const __half2* pt = ptw + hsel * 20;
    __half2 a0 = __floats2half2_rn(0.f, 0.f);
    __half2 a1 = __floats2half2_rn(0.f, 0.f);
    __half2 a2 = __floats2half2_rn(0.f, 0.f);
    __half2 a3 = __floats2half2_rn(0.f, 0.f);
    for (int e = 0; e < cm; e += 8) {  // pad entries are (p=0, off=0): safe
      int4 s4 = *(const int4*)&so[e];
      int4 s8 = *(const int4*)&so[e + 4];
      uint4 pwA = *(const uint4*)&pt[e];
      uint4 pwB = *(const uint4*)&pt[e + 4];
      const __half2* ppA = (const __half2*)&pwA;
      const __half2* ppB = (const __half2*)&pwB;
      uint4 hA = *(const uint4*)(h1l + (unsigned)s4.x);
      uint4 hB = *(const uint4*)(h1l + (unsigned)s4.y);
      uint4 hC = *(const uint4*)(h1l + (unsigned)s4.z);
      uint4 hD = *(const uint4*)(h1l + (unsigned)s4.w);
      uint4 hE = *(const uint4*)(h1l + (unsigned)s8.x);
      uint4 hF = *(const uint4*)(h1l + (unsigned)s8.y);
      uint4 hG = *(const uint4*)(h1l + (unsigned)s8.z);
      uint4 hH = *(const uint4*)(h1l + (unsigned)s8.w);
      const __half2* vA = (const __half2*)&hA;
      const __half2* vB = (const __half2*)&hB;
      const __half2* vC = (const __half2*)&hC;
      const __half2* vD = (const __half2*)&hD;
      const __half2* vE = (const __half2*)&hE;
      const __half2* vF = (const __half2*)&hF;
      const __half2* vG = (const __half2*)&hG;
      const __half2* vH = (const __half2*)&hH;
      a0 = __hfma2(vA[0], ppA[0], a0); a1 = __hfma2(vA[1], ppA[0], a1);
      a2 = __hfma2(vA[2], ppA[0], a2); a3 = __hfma2(vA[3], ppA[0], a3);
      a0 = __hfma2(vB[0], ppA[1], a0); a1 = __hfma2(vB[1], ppA[1], a1);
      a2 = __hfma2(vB[2], ppA[1], a2); a3 = __hfma2(vB[3], ppA[1], a3);
      a0 = __hfma2(vC[0], ppA[2], a0); a1 = __hfma2(vC[1], ppA[2], a1);
      a2 = __hfma2(vC[2], ppA[2], a2); a3 = __hfma2(vC[3], ppA[2], a3);
      a0 = __hfma2(vD[0], ppA[3], a0); a1 = __hfma2(vD[1], ppA[3], a1);
      a2 = __hfma2(vD[2], ppA[3], a2); a3 = __hfma2(vD[3], ppA[3], a3);
      a0 = __hfma2(vE[0], ppB[0], a0); a1 = __hfma2(vE[1], ppB[0], a1);
      a2 = __hfma2(vE[2], ppB[0], a2); a3 = __hfma2(vE[3], ppB[0], a3);
      a0 = __hfma2(vF[0], ppB[1], a0); a1 = __hfma2(vF[1], ppB[1], a1);
      a2 = __hfma2(vF[2], ppB[1], a2); a3 = __hfma2(vF[3], ppB[1], a3);
      a0 = __hfma2(vG[0], ppB[2], a0); a1 = __hfma2(vG[1], ppB[2], a1);
      a2 = __hfma2(vG[2], ppB[2], a2); a3 = __hfma2(vG[3], ppB[2], a3);
      a0 = __hfma2(vH[0], ppB[3], a0); a1 = __hfma2(vH[1], ppB[3], a1);
      a2 = __hfma2(vH[2], ppB[3], a2); a3 = __hfma2(vH[3], ppB[3], a3);
      den += __low2float(ppA[0]) + __low2float(ppA[1]) +
             __low2float(ppA[2]) + __low2float(ppA[3]) +
             __low2float(ppB[0]) + __low2float(ppB[1]) +
             __low2float(ppB[2]) + __low2float(ppB[3]);
    }
    // promote chunk accumulators to fp32
    float2 f0 = __half22float2(a0), f1 = __half22float2(a1);
    float2 f2 = __half22float2(a2), f3 = __half22float2(a3);
    accf[0] += f0.x; accf[1] += f0.y; accf[2] += f1.x; accf[3] += f1.y;
    accf[4] += f2.x; accf[5] += f2.y; accf[6] += f3.x; accf[7] += f3.y;
    asm volatile("s_waitcnt lgkmcnt(0)" ::: "memory");
  }

  // normalize by own head's den, fold in 1/8 head-mean
  float sc = 0.125f / den;
#pragma unroll
  for (int k = 0; k < 8; k++) accf[k] *= sc;
  // sum over heads: xor 2,4,8 within the 16-lane group
#pragma unroll
  for (int off = 2; off <= 8; off <<= 1) {
#pragma unroll
    for (int k = 0; k < 8; k++) accf[k] += __shfl_xor(accf[k], off);
  }
  // lane holds mean for ch (li&1)*8 + k
  int jb = (li & 1) * 8;
  float4 b1a = *(const float4*)(b1 + jb);
  float4 b1b = *(const float4*)(b1 + jb + 4);
  float bv[8] = {b1a.x, b1a.y, b1a.z, b1a.w, b1b.x, b1b.y, b1b.z, b1b.w};
  float r[8];
#pragma unroll
  for (int k = 0; k < 8; k++) {
    float v = accf[k] + bv[k];
    r[k] = v > 0.f ? v : __expf(v) - 1.f;
  }

  // store h1out (li=0: ch0-7, li=1: ch8-15) as one uint4 each
  if (li < 2) {
    uint4 pk;
    __half2* ph = (__half2*)&pk;
    ph[0] = __floats2half2_rn(r[0], r[1]);
    ph[1] = __floats2half2_rn(r[2], r[3]);
    ph[2] = __floats2half2_rn(r[4], r[5]);
    ph[3] = __floats2half2_rn(r[6], r[7]);
    *(uint4*)(h1o + (size_t)d * 16 + li * 8) = pk;
  }
  // as2/ad2 via projected att vectors
  float4 vaA = *(const float4*)(va + jb);
  float4 vaB = *(const float4*)(va + jb + 4);
  float4 vdA = *(const float4*)(vd + jb);
  float4 vdB = *(const float4*)(vd + jb + 4);
  float sv = r[0] * vaA.x + r[1] * vaA.y + r[2] * vaA.z + r[3] * vaA.w +
             r[4] * vaB.x + r[5] * vaB.y + r[6] * vaB.z + r[7] * vaB.w;
  float dv = r[0] * vdA.x + r[1] * vdA.y + r[2] * vdA.z + r[3] * vdA.w +
             r[4] * vdB.x + r[5] * vdB.y + r[6] * vdB.z + r[7] * vdB.w;
  sv += __shfl_xor(sv, 1);
  dv += __shfl_xor(dv, 1);
  if (li == 0) { as2[d] = sv; ad2[d] = dv; }
}

// ---------------- global max of as2 ----------------

__global__ __launch_bounds__(256) void k_maxas2(const float* __restrict__ as2,
                                                unsigned* __restrict__ enc) {
  int t = blockIdx.x * 256 + threadIdx.x;  // 64 blocks -> 16384 threads
  float mx = -1e30f;
  for (int r = t; r < N_NODES; r += 16384) mx = fmaxf(mx, as2[r]);
#pragma unroll
  for (int off = 32; off; off >>= 1) mx = fmaxf(mx, __shfl_xor(mx, off));
  if ((threadIdx.x & 63) == 0) atomicMax(enc, encf(mx));
}

// ---------------- conv2 aggregation: gather h1out (32B/edge), W2 at end -----
// lane = 8 channel-pairs x 8 edge-slots; per-dst 16x40 matvec + log_softmax.

__global__ __launch_bounds__(256) void k_agg2(
    const __half* __restrict__ h1o, const float* __restrict__ as2,
    const float* __restrict__ ad2, const int* __restrict__ start,
    const int* __restrict__ esrc, const float* __restrict__ b2,
    const float* __restrict__ W2, const unsigned* __restrict__ as2maxEnc,
    float* __restrict__ out) {
  __shared__ __align__(16) float p_l[4][64];
  __shared__ __align__(16) int s_l[4][64];  // byte offsets (s*32)
  __shared__ float w2s[16 * 40];
  int t = threadIdx.x;
  for (int i = t; i < 640; i += 256) w2s[i] = W2[i];
  __syncthreads();

  int wave = t >> 6, lane = t & 63;
  int d = blockIdx.x * 4 + wave;
  if (d >= N_NODES) return;
  int s0 = start[d];
  int deg = start[d + 1] - s0;
  float adv = ad2[d];
  float cm = decf(as2maxEnc[0]) + adv;
  cm = cm > 0.f ? cm : 0.2f * cm;

  int cp = lane & 7;   // channel pair (ch 2cp, 2cp+1)
  int es = lane >> 3;  // edge slot 0..7
  const char* hb = (const char*)h1o + cp * 4;

  float den = 0.f, acc0 = 0.f, acc1 = 0.f;
  for (int be = 0; be < deg; be += 64) {
    int cnt = min(64, deg - be);
    if (lane < cnt) {
      int s = esrc[s0 + be + lane];
      s_l[wave][lane] = s * 32;  // byte offset into h1o (16 halves)
      float e = as2[s] + adv;
      e = e > 0.f ? e : 0.2f * e;
      float p = __expf(e - cm);
      den += p;
      p_l[wave][lane] = p;
    }
    asm volatile("s_waitcnt lgkmcnt(0)" ::: "memory");
    int i = es;
    for (; i + 8 < cnt; i += 16) {
      int sbA = s_l[wave][i], sbB = s_l[wave][i + 8];
      float pA = p_l[wave][i], pB = p_l[wave][i + 8];
      __half2 hvA = *(const __half2*)(hb + (unsigned)sbA);
      __half2 hvB = *(const __half2*)(hb + (unsigned)sbB);
      acc0 = fmaf(__half2float(hvA.x), pA, acc0);
      acc1 = fmaf(__half2float(hvA.y), pA, acc1);
      acc0 = fmaf(__half2float(hvB.x), pB, acc0);
      acc1 = fmaf(__half2float(hvB.y), pB, acc1);
    }
    if (i < cnt) {
      int sb = s_l[wave][i];
      float p = p_l[wave][i];
      __half2 hv = *(const __half2*)(hb + (unsigned)sb);
      acc0 = fmaf(__half2float(hv.x), p, acc0);
      acc1 = fmaf(__half2float(hv.y), p, acc1);
    }
    asm volatile("s_waitcnt lgkmcnt(0)" ::: "memory");
  }
#pragma unroll
  for (int off = 32; off; off >>= 1) den += __shfl_xor(den, off);
  float iv = 1.f / den;

  // combine 8 edge-slots (lanes sharing cp): xor 8,16,32
  acc0 += __shfl_xor(acc0, 8);  acc1 += __shfl_xor(acc1, 8);
  acc0 += __shfl_xor(acc0, 16); acc1 += __shfl_xor(acc1, 16);
  acc0 += __shfl_xor(acc0, 32); acc1 += __shfl_xor(acc1, 32);
  float m0 = acc0 * iv, m1 = acc1 * iv;

  // matvec: out_j = sum_k m_k W2[k][j] + b2[j], j = lane < 40
  float v = 0.f;
#pragma unroll
  for (int k = 0; k < 16; k++) {
    float ms = (k & 1) ? m1 : m0;
    float mk = __shfl(ms, k >> 1);
    if (lane < N_CLS) v = fmaf(mk, w2s[k * 40 + lane], v);
  }
  v = (lane < N_CLS) ? v + b2[lane] : -1e30f;

  float mx = v;
#pragma unroll
  for (int off = 32; off; off >>= 1) mx = fmaxf(mx, __shfl_xor(mx, off));
  float ex = (lane < N_CLS) ? __expf(v - mx) : 0.f;
  float sm = ex;
#pragma unroll
  for (int off = 32; off; off >>= 1) sm += __shfl_xor(sm, off);
  float lse = logf(sm);
  if (lane < N_CLS) out[d * N_CLS + lane] = (v - mx) - lse;
}

// ---------------- host launcher ----------------

extern "C" void kernel_launch(void* const* d_in, const int* in_sizes, int n_in,
                              void* d_out, int out_size, void* d_ws, size_t ws_size,
                              hipStream_t stream) {
  const float* x    = (const float*)d_in[0];
  const int*   ei   = (const int*)d_in[1];
  const float* W1   = (const float*)d_in[2];
  const float* as1w = (const float*)d_in[3];
  const float* ad1w = (const float*)d_in[4];
  const float* b1   = (const float*)d_in[5];
  const float* W2   = (const float*)d_in[6];
  const float* as2w = (const float*)d_in[7];
  const float* ad2w = (const float*)d_in[8];
  const float* b2   = (const float*)d_in[9];
  float* out = (float*)d_out;

  char* ws = (char*)d_ws;
  size_t off = 0;
  auto alloc = [&](size_t bytes) -> void* {
    void* p = ws + off;
    off += (bytes + 255) & ~(size_t)255;
    return p;
  };
  __half* h1   = (__half*)alloc((size_t)N_NODES * 128 * 2);
  float* as1   = (float*)alloc((size_t)N_NODES * 8 * 4);
  float* ad1   = (float*)alloc((size_t)N_NODES * 8 * 4);
  __half* h1o  = (__half*)alloc((size_t)N_NODES * 16 * 2);
  float* as2   = (float*)alloc((size_t)N_NODES * 4);
  float* ad2   = (float*)alloc((size_t)N_NODES * 4);
  unsigned* maxenc = (unsigned*)alloc(256);  // [0..7]=as1 heads, [8]=as2
  int* start   = (int*)alloc((size_t)(N_NODES + 1) * 4);
  int* esrc    = (int*)alloc((size_t)ET * 4);
  int2* eb     = (int2*)alloc((size_t)ET * 8);
  int* bcnt    = (int*)alloc((size_t)NBK * NSB * 4);
  int* boffs   = (int*)alloc((size_t)NBK * NSB * 4);
  int* btot    = (int*)alloc((size_t)NBK * 4);
  int* bstart  = (int*)alloc((size_t)NBK * 4);
  float* fmax1 = (float*)alloc(32);
  float* va    = (float*)alloc(64);
  float* vd    = (float*)alloc(64);

  (void)hipMemsetAsync(maxenc, 0, 256, stream);

  k_xform1<<<XB, 256, 0, stream>>>(x, W1, as1w, ad1w, h1, as1, ad1, maxenc);
  k_rxA<<<NSB, 256, 0, stream>>>(ei, bcnt);
  k_rxScanB<<<NBK, 256, 0, stream>>>(bcnt, boffs, btot);
  k_rxTot<<<1, 256, 0, stream>>>(btot, bstart, start, maxenc, fmax1,
                                 W2, as2w, ad2w, va, vd);
  k_rxScat<<<NSB, 256, 0, stream>>>(ei, bstart, boffs, eb);
  k_rxB<<<NBK, 256, 0, stream>>>(eb, bstart, start, esrc);

  k_agg1<<<N_NODES / 16, 256, 0, stream>>>(h1, as1, ad1, start, esrc, b1,
                                           va, vd, fmax1, h1o, as2, ad2);
  k_maxas2<<<64, 256, 0, stream>>>(as2, maxenc + 8);
  k_agg2<<<(N_NODES + 3) / 4, 256, 0, stream>>>(h1o, as2, ad2, start, esrc, b2,
                                                W2, maxenc + 8, out);
}

// Round 21
// 151.950 us; speedup vs baseline: 1.2375x; 1.0315x over previous
//
#include <hip/hip_runtime.h>
#include <hip/hip_fp16.h>
#include <math.h>

#define N_NODES 50000
#define N_EDGES 1000000
#define F_IN 128
#define HID 16
#define N_CLS 40
#define HEADS 8
#define ET (N_EDGES + N_NODES)
#define XB ((N_NODES + 63) / 64)   // 782 xform blocks
#define NBK 196                    // coarse buckets (dst >> 8)
#define NSB 256                    // scatter blocks
#define ECH ((ET + NSB - 1) / NSB) // 4103 edges per scatter block

__device__ __forceinline__ void fma4(float4& acc, float s, const float4& v) {
  acc.x += s * v.x;
  acc.y += s * v.y;
  acc.z += s * v.z;
  acc.w += s * v.w;
}

__device__ __forceinline__ float dot4(float4 a, float4 b) {
  return a.x * b.x + a.y * b.y + a.z * b.z + a.w * b.w;
}

// monotone float<->uint encoding for atomicMax on floats
__device__ __forceinline__ unsigned encf(float f) {
  unsigned b = __float_as_uint(f);
  return (b & 0x80000000u) ? ~b : (b | 0x80000000u);
}
__device__ __forceinline__ float decf(unsigned k) {
  unsigned b = (k & 0x80000000u) ? (k ^ 0x80000000u) : ~k;
  return __uint_as_float(b);
}

// ---------------- conv1 transform (+ fused coarse-histogram blocks) ---------
// Hist blocks (LDS counters, coalesced reads) overlap the compute blocks.

__global__ __launch_bounds__(256, 4) void k_xform1(
    const float* __restrict__ x, const float* __restrict__ W1,
    const float* __restrict__ att_s, const float* __restrict__ att_d,
    const int* __restrict__ ei, int* __restrict__ bcnt,
    __half* __restrict__ h1, float* __restrict__ as1, float* __restrict__ ad1,
    unsigned* __restrict__ enc1) {
  __shared__ float4 xlds[64 * 9];   // [node][k-quad within phase], padded
  __shared__ float4 wlds[32 * 33];  // [k within phase][c-quad], padded
  __shared__ unsigned encl[8];
  int t = threadIdx.x;

  if (blockIdx.x >= XB) {  // coarse histogram blocks (reuse xlds as counters)
    int* cnt = (int*)xlds;
    int blk = blockIdx.x - XB;
    if (t < NBK) cnt[t] = 0;
    __syncthreads();
    int lo = blk * ECH + t;
    int hi = min((blk + 1) * ECH, ET);
    for (int i = lo; i < hi; i += 256) {
      int d = (i < N_EDGES) ? ei[N_EDGES + i] : (i - N_EDGES);
      atomicAdd(&cnt[d >> 8], 1);
    }
    __syncthreads();
    if (t < NBK) bcnt[t * NSB + blk] = cnt[t];
    return;
  }

  if (t < 8) encl[t] = 0u;
  int tx = t & 15, ty = t >> 4;
  int base = blockIdx.x * 64;
  const float4* x4 = (const float4*)x;
  const float4* W4 = (const float4*)W1;

  float4 accA[4], accB[4];
#pragma unroll
  for (int n = 0; n < 4; n++) {
    accA[n] = {0.f, 0.f, 0.f, 0.f};
    accB[n] = {0.f, 0.f, 0.f, 0.f};
  }
  int n0 = ty * 4;

  for (int kb = 0; kb < 4; kb++) {
    __syncthreads();
    {
      int i = t;
      int n = i >> 3, q = i & 7;
      int gn = base + n;
      float4 v = {0.f, 0.f, 0.f, 0.f};
      if (gn < N_NODES) v = x4[(size_t)gn * 32 + kb * 8 + q];
      xlds[n * 9 + q] = v;
      i += 256;
      n = i >> 3; q = i & 7;
      gn = base + n;
      float4 v2 = {0.f, 0.f, 0.f, 0.f};
      if (gn < N_NODES) v2 = x4[(size_t)gn * 32 + kb * 8 + q];
      xlds[n * 9 + q] = v2;
    }
#pragma unroll
    for (int u = 0; u < 4; u++) {
      int i = t + u * 256;
      int r = i >> 5, q = i & 31;
      wlds[r * 33 + q] = W4[(size_t)(kb * 32 + r) * 32 + q];
    }
    __syncthreads();
#pragma unroll
    for (int kk = 0; kk < 8; kk++) {
      float4 xv0 = xlds[(n0 + 0) * 9 + kk];
      float4 xv1 = xlds[(n0 + 1) * 9 + kk];
      float4 xv2 = xlds[(n0 + 2) * 9 + kk];
      float4 xv3 = xlds[(n0 + 3) * 9 + kk];
#pragma unroll
      for (int j = 0; j < 4; j++) {
        float4 wA = wlds[(kk * 4 + j) * 33 + tx];
        float4 wB = wlds[(kk * 4 + j) * 33 + tx + 16];
        float s0 = (j == 0) ? xv0.x : (j == 1) ? xv0.y : (j == 2) ? xv0.z : xv0.w;
        float s1 = (j == 0) ? xv1.x : (j == 1) ? xv1.y : (j == 2) ? xv1.z : xv1.w;
        float s2 = (j == 0) ? xv2.x : (j == 1) ? xv2.y : (j == 2) ? xv2.z : xv2.w;
        float s3 = (j == 0) ? xv3.x : (j == 1) ? xv3.y : (j == 2) ? xv3.z : xv3.w;
        fma4(accA[0], s0, wA); fma4(accB[0], s0, wB);
        fma4(accA[1], s1, wA); fma4(accB[1], s1, wB);
        fma4(accA[2], s2, wA); fma4(accB[2], s2, wB);
        fma4(accA[3], s3, wA); fma4(accB[3], s3, wB);
      }
    }
  }

  int c4 = tx * 4;
  float4 asA = *(const float4*)(att_s + c4);
  float4 asB = *(const float4*)(att_s + 64 + c4);
  float4 adA = *(const float4*)(att_d + c4);
  float4 adB = *(const float4*)(att_d + 64 + c4);
  float mxA = -1e30f, mxB = -1e30f;
#pragma unroll
  for (int n = 0; n < 4; n++) {
    int gn = base + n0 + n;
    float psA = dot4(accA[n], asA);
    float psB = dot4(accB[n], asB);
    float pdA = dot4(accA[n], adA);
    float pdB = dot4(accB[n], adB);
    psA += __shfl_xor(psA, 1); psA += __shfl_xor(psA, 2);
    psB += __shfl_xor(psB, 1); psB += __shfl_xor(psB, 2);
    pdA += __shfl_xor(pdA, 1); pdA += __shfl_xor(pdA, 2);
    pdB += __shfl_xor(pdB, 1); pdB += __shfl_xor(pdB, 2);
    if (gn < N_NODES) {
      uint2 pkA, pkB;
      __half2* phA = (__half2*)&pkA;
      __half2* phB = (__half2*)&pkB;
      phA[0] = __floats2half2_rn(accA[n].x, accA[n].y);
      phA[1] = __floats2half2_rn(accA[n].z, accA[n].w);
      phB[0] = __floats2half2_rn(accB[n].x, accB[n].y);
      phB[1] = __floats2half2_rn(accB[n].z, accB[n].w);
      *(uint2*)(h1 + (size_t)gn * 128 + c4) = pkA;
      *(uint2*)(h1 + (size_t)gn * 128 + 64 + c4) = pkB;
      mxA = fmaxf(mxA, psA);
      mxB = fmaxf(mxB, psB);
      if ((tx & 3) == 0) {
        as1[gn * 8 + (tx >> 2)] = psA;
        as1[gn * 8 + 4 + (tx >> 2)] = psB;
        ad1[gn * 8 + (tx >> 2)] = pdA;
        ad1[gn * 8 + 4 + (tx >> 2)] = pdB;
      }
    }
  }
  if ((tx & 3) == 0) {
    atomicMax(&encl[tx >> 2], encf(mxA));
    atomicMax(&encl[4 + (tx >> 2)], encf(mxB));
  }
  __syncthreads();
  if (t < 8) atomicMax(&enc1[t], encl[t]);
}

// ---------------- radix CSR build (packed edge records) ----------------

__global__ __launch_bounds__(256) void k_rxScanB(const int* __restrict__ bcnt,
                                                 int* __restrict__ boffs,
                                                 int* __restrict__ btot) {
  __shared__ int s[256];
  int b = blockIdx.x, t = threadIdx.x;
  int v0 = bcnt[b * NSB + t];
  s[t] = v0;
  __syncthreads();
  for (int off = 1; off < 256; off <<= 1) {
    int v = (t >= off) ? s[t - off] : 0;
    __syncthreads();
    s[t] += v;
    __syncthreads();
  }
  boffs[b * NSB + t] = s[t] - v0;
  if (t == 255) btot[b] = s[255];
}

// bucket-total scan + fmax decode + va/vd = W2-projected att vectors

__global__ __launch_bounds__(256) void k_rxTot(const int* __restrict__ btot,
                                               int* __restrict__ bstart,
                                               int* __restrict__ start,
                                               const unsigned* __restrict__ enc1,
                                               float* __restrict__ fmax1,
                                               const float* __restrict__ W2,
                                               const float* __restrict__ att_s2,
                                               const float* __restrict__ att_d2,
                                               float* __restrict__ va,
                                               float* __restrict__ vd) {
  __shared__ int s[256];
  int t = threadIdx.x;
  int v0 = (t < NBK) ? btot[t] : 0;
  s[t] = v0;
  __syncthreads();
  for (int off = 1; off < 256; off <<= 1) {
    int v = (t >= off) ? s[t - off] : 0;
    __syncthreads();
    s[t] += v;
    __syncthreads();
  }
  if (t < NBK) bstart[t] = s[t] - v0;
  if (t == 0) start[N_NODES] = ET;
  if (t < 8) fmax1[t] = decf(enc1[t]);
  if (t < 16) {
    float a = 0.f, dd = 0.f;
    for (int j = 0; j < N_CLS; j++) {
      float w = W2[t * N_CLS + j];
      a = fmaf(w, att_s2[j], a);
      dd = fmaf(w, att_d2[j], dd);
    }
    va[t] = a;
    vd[t] = dd;
  }
}

__global__ __launch_bounds__(256) void k_rxScat(const int* __restrict__ ei,
                                                const int* __restrict__ bstart,
                                                const int* __restrict__ boffs,
                                                int* __restrict__ eb) {
  __shared__ int cur[NBK];
  int t = threadIdx.x, blk = blockIdx.x;
  if (t < NBK) cur[t] = bstart[t] + boffs[t * NSB + blk];
  __syncthreads();
  int lo = blk * ECH + t;
  int hi = min((blk + 1) * ECH, ET);
  for (int i = lo; i < hi; i += 256) {
    int s, d;
    if (i < N_EDGES) { s = ei[i]; d = ei[N_EDGES + i]; }
    else { s = i - N_EDGES; d = s; }
    int pos = atomicAdd(&cur[d >> 8], 1);
    eb[pos] = s | ((d & 255) << 16);  // s < 65536
  }
}

__global__ __launch_bounds__(256) void k_rxB(const int* __restrict__ eb,
                                             const int* __restrict__ bstart,
                                             int* __restrict__ start,
                                             int* __restrict__ esrc) {
  __shared__ int dcnt[256], lst[256], ssc[256];
  __shared__ int esl[8192];  // bucket cap (mean 5357, +39 sigma)
  int t = threadIdx.x, b = blockIdx.x;
  int nlo = b * 256;
  int nn = min(256, N_NODES - nlo);
  int e0 = bstart[b];
  int e1 = (b == NBK - 1) ? ET : bstart[b + 1];
  int cnt = e1 - e0;
  dcnt[t] = 0;
  __syncthreads();
  for (int e = t; e < cnt; e += 256) atomicAdd(&dcnt[(eb[e0 + e] >> 16) & 255], 1);
  __syncthreads();
  int v0 = dcnt[t];
  ssc[t] = v0;
  __syncthreads();
  for (int off = 1; off < 256; off <<= 1) {
    int v = (t >= off) ? ssc[t - off] : 0;
    __syncthreads();
    ssc[t] += v;
    __syncthreads();
  }
  lst[t] = ssc[t] - v0;  // exclusive
  if (t < nn) start[nlo + t] = e0 + lst[t];
  dcnt[t] = lst[t];      // reuse as cursor
  __syncthreads();
  for (int e = t; e < cnt; e += 256) {
    int v = eb[e0 + e];
    int pos = atomicAdd(&dcnt[(v >> 16) & 255], 1);
    esl[pos] = v & 0xFFFF;
  }
  __syncthreads();
  for (int e = t; e < cnt; e += 256) esrc[e0 + e] = esl[e];
}

// ---------------- conv1 aggregation (h2 eliminated by linearity) -----------
// Outputs h1out[N,16] f16 + as2 = h1out.va, ad2 = h1out.vd.

__global__ __launch_bounds__(256) void k_agg1(
    const __half* __restrict__ h1, const float* __restrict__ as1,
    const float* __restrict__ ad1, const int* __restrict__ start,
    const int* __restrict__ esrc, const float* __restrict__ b1,
    const float* __restrict__ va, const float* __restrict__ vd,
    const float* __restrict__ fmax1,
    __half* __restrict__ h1o, float* __restrict__ as2, float* __restrict__ ad2) {
  __shared__ __align__(16) __half2 p_t[4][4 * 164];  // [wave][g*164 + head*20 + e]
  __shared__ __align__(16) int s_off[4][4][20];      // [wave][g][16e+pad]
  int t = threadIdx.x;

  int wave = t >> 6, lane = t & 63;
  int g = lane >> 4, li = lane & 15;
  int d = blockIdx.x * 16 + wave * 4 + g;  // 3125*16 = 50000 exact
  int s0 = start[d];
  int deg = start[d + 1] - s0;

  int dm = deg;
  dm = max(dm, __shfl_xor(dm, 16));
  dm = max(dm, __shfl_xor(dm, 32));

  float4 av0 = *(const float4*)(ad1 + d * 8);
  float4 av1 = *(const float4*)(ad1 + d * 8 + 4);
  float ad_[8] = {av0.x, av0.y, av0.z, av0.w, av1.x, av1.y, av1.z, av1.w};
  float c_[8];
#pragma unroll
  for (int h = 0; h < 8; h++) {
    float e = fmax1[h] + ad_[h];
    c_[h] = e > 0.f ? e : 0.2f * e;
  }

  float den = 0.f;
  float accf[8];
#pragma unroll
  for (int k = 0; k < 8; k++) accf[k] = 0.f;

  int hsel = li >> 1;
  const char* h1l = (const char*)(h1 + li * 8);  // lane's 16B channel chunk
  __half2* ptw = &p_t[wave][g * 164];
  const int* so = &s_off[wave][g][0];

  for (int be = 0; be < dm; be += 16) {
    int cnt = deg - be;  // may be <= 0
    bool act = li < cnt;
    int s = 0;
    if (act) s = esrc[s0 + be + li];
    s_off[wave][g][li] = act ? (s << 8) : 0;
    float4 p0 = {0.f, 0.f, 0.f, 0.f}, p1 = {0.f, 0.f, 0.f, 0.f};
    if (act) {
      p0 = *(const float4*)(as1 + (size_t)s * 8);
      p1 = *(const float4*)(as1 + (size_t)s * 8 + 4);
    }
    float ev[8] = {p0.x, p0.y, p0.z, p0.w, p1.x, p1.y, p1.z, p1.w};
#pragma unroll
    for (int h = 0; h < 8; h++) {
      float v = ev[h] + ad_[h];
      v = v > 0.f ? v : 0.2f * v;
      float pv = act ? __expf(v - c_[h]) : 0.f;
      __half hp = __float2half(pv);
      ptw[h * 20 + li] = __half2{hp, hp};
    }
    asm volatile("s_waitcnt lgkmcnt(0)" ::: "memory");

    int cm = min(dm - be, 16);
    const __half2* pt = ptw + hsel * 20;
    __half2 a0 = __floats2half2_rn(0.f, 0.f);
    __half2 a1 = __floats2half2_rn(0.f, 0.f);
    __half2 a2 = __floats2half2_rn(0.f, 0.f);
    __half2 a3 = __floats2half2_rn(0.f, 0.f);
    for (int e = 0; e < cm; e += 8) {  // pad entries are (p=0, off=0): safe
      int4 s4 = *(const int4*)&so[e];
      int4 s8 = *(const int4*)&so[e + 4];
      uint4 pwA = *(const uint4*)&pt[e];
      uint4 pwB = *(const uint4*)&pt[e + 4];
      const __half2* ppA = (const __half2*)&pwA;
      const __half2* ppB = (const __half2*)&pwB;
      uint4 hA = *(const uint4*)(h1l + (unsigned)s4.x);
      uint4 hB = *(const uint4*)(h1l + (unsigned)s4.y);
      uint4 hC = *(const uint4*)(h1l + (unsigned)s4.z);
      uint4 hD = *(const uint4*)(h1l + (unsigned)s4.w);
      uint4 hE = *(const uint4*)(h1l + (unsigned)s8.x);
      uint4 hF = *(const uint4*)(h1l + (unsigned)s8.y);
      uint4 hG = *(const uint4*)(h1l + (unsigned)s8.z);
      uint4 hH = *(const uint4*)(h1l + (unsigned)s8.w);
      const __half2* vA = (const __half2*)&hA;
      const __half2* vB = (const __half2*)&hB;
      const __half2* vC = (const __half2*)&hC;
      const __half2* vD = (const __half2*)&hD;
      const __half2* vE = (const __half2*)&hE;
      const __half2* vF = (const __half2*)&hF;
      const __half2* vG = (const __half2*)&hG;
      const __half2* vH = (const __half2*)&hH;
      a0 = __hfma2(vA[0], ppA[0], a0); a1 = __hfma2(vA[1], ppA[0], a1);
      a2 = __hfma2(vA[2], ppA[0], a2); a3 = __hfma2(vA[3], ppA[0], a3);
      a0 = __hfma2(vB[0], ppA[1], a0); a1 = __hfma2(vB[1], ppA[1], a1);
      a2 = __hfma2(vB[2], ppA[1], a2); a3 = __hfma2(vB[3], ppA[1], a3);
      a0 = __hfma2(vC[0], ppA[2], a0); a1 = __hfma2(vC[1], ppA[2], a1);
      a2 = __hfma2(vC[2], ppA[2], a2); a3 = __hfma2(vC[3], ppA[2], a3);
      a0 = __hfma2(vD[0], ppA[3], a0); a1 = __hfma2(vD[1], ppA[3], a1);
      a2 = __hfma2(vD[2], ppA[3], a2); a3 = __hfma2(vD[3], ppA[3], a3);
      a0 = __hfma2(vE[0], ppB[0], a0); a1 = __hfma2(vE[1], ppB[0], a1);
      a2 = __hfma2(vE[2], ppB[0], a2); a3 = __hfma2(vE[3], ppB[0], a3);
      a0 = __hfma2(vF[0], ppB[1], a0); a1 = __hfma2(vF[1], ppB[1], a1);
      a2 = __hfma2(vF[2], ppB[1], a2); a3 = __hfma2(vF[3], ppB[1], a3);
      a0 = __hfma2(vG[0], ppB[2], a0); a1 = __hfma2(vG[1], ppB[2], a1);
      a2 = __hfma2(vG[2], ppB[2], a2); a3 = __hfma2(vG[3], ppB[2], a3);
      a0 = __hfma2(vH[0], ppB[3], a0); a1 = __hfma2(vH[1], ppB[3], a1);
      a2 = __hfma2(vH[2], ppB[3], a2); a3 = __hfma2(vH[3], ppB[3], a3);
      den += __low2float(ppA[0]) + __low2float(ppA[1]) +
             __low2float(ppA[2]) + __low2float(ppA[3]) +
             __low2float(ppB[0]) + __low2float(ppB[1]) +
             __low2float(ppB[2]) + __low2float(ppB[3]);
    }
    // promote chunk accumulators to fp32
    float2 f0 = __half22float2(a0), f1 = __half22float2(a1);
    float2 f2 = __half22float2(a2), f3 = __half22float2(a3);
    accf[0] += f0.x; accf[1] += f0.y; accf[2] += f1.x; accf[3] += f1.y;
    accf[4] += f2.x; accf[5] += f2.y; accf[6] += f3.x; accf[7] += f3.y;
    asm volatile("s_waitcnt lgkmcnt(0)" ::: "memory");
  }

  // normalize by own head's den, fold in 1/8 head-mean
  float sc = 0.125f / den;
#pragma unroll
  for (int k = 0; k < 8; k++) accf[k] *= sc;
  // sum over heads: xor 2,4,8 within the 16-lane group
#pragma unroll
  for (int off = 2; off <= 8; off <<= 1) {
#pragma unroll
    for (int k = 0; k < 8; k++) accf[k] += __shfl_xor(accf[k], off);
  }
  // lane holds mean for ch (li&1)*8 + k
  int jb = (li & 1) * 8;
  float4 b1a = *(const float4*)(b1 + jb);
  float4 b1b = *(const float4*)(b1 + jb + 4);
  float bv[8] = {b1a.x, b1a.y, b1a.z, b1a.w, b1b.x, b1b.y, b1b.z, b1b.w};
  float r[8];
#pragma unroll
  for (int k = 0; k < 8; k++) {
    float v = accf[k] + bv[k];
    r[k] = v > 0.f ? v : __expf(v) - 1.f;
  }

  // store h1out (li=0: ch0-7, li=1: ch8-15) as one uint4 each
  if (li < 2) {
    uint4 pk;
    __half2* ph = (__half2*)&pk;
    ph[0] = __floats2half2_rn(r[0], r[1]);
    ph[1] = __floats2half2_rn(r[2], r[3]);
    ph[2] = __floats2half2_rn(r[4], r[5]);
    ph[3] = __floats2half2_rn(r[6], r[7]);
    *(uint4*)(h1o + (size_t)d * 16 + li * 8) = pk;
  }
  // as2/ad2 via projected att vectors
  float4 vaA = *(const float4*)(va + jb);
  float4 vaB = *(const float4*)(va + jb + 4);
  float4 vdA = *(const float4*)(vd + jb);
  float4 vdB = *(const float4*)(vd + jb + 4);
  float sv = r[0] * vaA.x + r[1] * vaA.y + r[2] * vaA.z + r[3] * vaA.w +
             r[4] * vaB.x + r[5] * vaB.y + r[6] * vaB.z + r[7] * vaB.w;
  float dv = r[0] * vdA.x + r[1] * vdA.y + r[2] * vdA.z + r[3] * vdA.w +
             r[4] * vdB.x + r[5] * vdB.y + r[6] * vdB.z + r[7] * vdB.w;
  sv += __shfl_xor(sv, 1);
  dv += __shfl_xor(dv, 1);
  if (li == 0) { as2[d] = sv; ad2[d] = dv; }
}

// ---------------- global max of as2 ----------------

__global__ __launch_bounds__(256) void k_maxas2(const float* __restrict__ as2,
                                                unsigned* __restrict__ enc) {
  int t = blockIdx.x * 256 + threadIdx.x;  // 64 blocks -> 16384 threads
  float mx = -1e30f;
  for (int r = t; r < N_NODES; r += 16384) mx = fmaxf(mx, as2[r]);
#pragma unroll
  for (int off = 32; off; off >>= 1) mx = fmaxf(mx, __shfl_xor(mx, off));
  if ((threadIdx.x & 63) == 0) atomicMax(enc, encf(mx));
}

// ---------------- conv2 aggregation: gather h1out (32B/edge), W2 at end -----
// lane = 8 channel-pairs x 8 edge-slots; per-dst 16x40 matvec + log_softmax.

__global__ __launch_bounds__(256) void k_agg2(
    const __half* __restrict__ h1o, const float* __restrict__ as2,
    const float* __restrict__ ad2, const int* __restrict__ start,
    const int* __restrict__ esrc, const float* __restrict__ b2,
    const float* __restrict__ W2, const unsigned* __restrict__ as2maxEnc,
    float* __restrict__ out) {
  __shared__ __align__(16) float p_l[4][64];
  __shared__ __align__(16) int s_l[4][64];  // byte offsets (s*32)
  __shared__ float w2s[16 * 40];
  int t = threadIdx.x;
  for (int i = t; i < 640; i += 256) w2s[i] = W2[i];
  __syncthreads();

  int wave = t >> 6, lane = t & 63;
  int d = blockIdx.x * 4 + wave;
  if (d >= N_NODES) return;
  int s0 = start[d];
  int deg = start[d + 1] - s0;
  float adv = ad2[d];
  float cm = decf(as2maxEnc[0]) + adv;
  cm = cm > 0.f ? cm : 0.2f * cm;

  int cp = lane & 7;   // channel pair (ch 2cp, 2cp+1)
  int es = lane >> 3;  // edge slot 0..7
  const char* hb = (const char*)h1o + cp * 4;

  float den = 0.f, acc0 = 0.f, acc1 = 0.f;
  for (int be = 0; be < deg; be += 64) {
    int cnt = min(64, deg - be);
    if (lane < cnt) {
      int s = esrc[s0 + be + lane];
      s_l[wave][lane] = s * 32;  // byte offset into h1o (16 halves)
      float e = as2[s] + adv;
      e = e > 0.f ? e : 0.2f * e;
      float p = __expf(e - cm);
      den += p;
      p_l[wave][lane] = p;
    }
    asm volatile("s_waitcnt lgkmcnt(0)" ::: "memory");
    int i = es;
    for (; i + 8 < cnt; i += 16) {
      int sbA = s_l[wave][i], sbB = s_l[wave][i + 8];
      float pA = p_l[wave][i], pB = p_l[wave][i + 8];
      __half2 hvA = *(const __half2*)(hb + (unsigned)sbA);
      __half2 hvB = *(const __half2*)(hb + (unsigned)sbB);
      acc0 = fmaf(__half2float(hvA.x), pA, acc0);
      acc1 = fmaf(__half2float(hvA.y), pA, acc1);
      acc0 = fmaf(__half2float(hvB.x), pB, acc0);
      acc1 = fmaf(__half2float(hvB.y), pB, acc1);
    }
    if (i < cnt) {
      int sb = s_l[wave][i];
      float p = p_l[wave][i];
      __half2 hv = *(const __half2*)(hb + (unsigned)sb);
      acc0 = fmaf(__half2float(hv.x), p, acc0);
      acc1 = fmaf(__half2float(hv.y), p, acc1);
    }
    asm volatile("s_waitcnt lgkmcnt(0)" ::: "memory");
  }
#pragma unroll
  for (int off = 32; off; off >>= 1) den += __shfl_xor(den, off);
  float iv = 1.f / den;

  // combine 8 edge-slots (lanes sharing cp): xor 8,16,32
  acc0 += __shfl_xor(acc0, 8);  acc1 += __shfl_xor(acc1, 8);
  acc0 += __shfl_xor(acc0, 16); acc1 += __shfl_xor(acc1, 16);
  acc0 += __shfl_xor(acc0, 32); acc1 += __shfl_xor(acc1, 32);
  float m0 = acc0 * iv, m1 = acc1 * iv;

  // matvec: out_j = sum_k m_k W2[k][j] + b2[j], j = lane < 40
  float v = 0.f;
#pragma unroll
  for (int k = 0; k < 16; k++) {
    float ms = (k & 1) ? m1 : m0;
    float mk = __shfl(ms, k >> 1);
    if (lane < N_CLS) v = fmaf(mk, w2s[k * 40 + lane], v);
  }
  v = (lane < N_CLS) ? v + b2[lane] : -1e30f;

  float mx = v;
#pragma unroll
  for (int off = 32; off; off >>= 1) mx = fmaxf(mx, __shfl_xor(mx, off));
  float ex = (lane < N_CLS) ? __expf(v - mx) : 0.f;
  float sm = ex;
#pragma unroll
  for (int off = 32; off; off >>= 1) sm += __shfl_xor(sm, off);
  float lse = logf(sm);
  if (lane < N_CLS) out[d * N_CLS + lane] = (v - mx) - lse;
}

// ---------------- host launcher ----------------

extern "C" void kernel_launch(void* const* d_in, const int* in_sizes, int n_in,
                              void* d_out, int out_size, void* d_ws, size_t ws_size,
                              hipStream_t stream) {
  const float* x    = (const float*)d_in[0];
  const int*   ei   = (const int*)d_in[1];
  const float* W1   = (const float*)d_in[2];
  const float* as1w = (const float*)d_in[3];
  const float* ad1w = (const float*)d_in[4];
  const float* b1   = (const float*)d_in[5];
  const float* W2   = (const float*)d_in[6];
  const float* as2w = (const float*)d_in[7];
  const float* ad2w = (const float*)d_in[8];
  const float* b2   = (const float*)d_in[9];
  float* out = (float*)d_out;

  char* ws = (char*)d_ws;
  size_t off = 0;
  auto alloc = [&](size_t bytes) -> void* {
    void* p = ws + off;
    off += (bytes + 255) & ~(size_t)255;
    return p;
  };
  __half* h1   = (__half*)alloc((size_t)N_NODES * 128 * 2);
  float* as1   = (float*)alloc((size_t)N_NODES * 8 * 4);
  float* ad1   = (float*)alloc((size_t)N_NODES * 8 * 4);
  __half* h1o  = (__half*)alloc((size_t)N_NODES * 16 * 2);
  float* as2   = (float*)alloc((size_t)N_NODES * 4);
  float* ad2   = (float*)alloc((size_t)N_NODES * 4);
  unsigned* maxenc = (unsigned*)alloc(256);  // [0..7]=as1 heads, [8]=as2
  int* start   = (int*)alloc((size_t)(N_NODES + 1) * 4);
  int* esrc    = (int*)alloc((size_t)ET * 4);
  int* eb      = (int*)alloc((size_t)ET * 4);
  int* bcnt    = (int*)alloc((size_t)NBK * NSB * 4);
  int* boffs   = (int*)alloc((size_t)NBK * NSB * 4);
  int* btot    = (int*)alloc((size_t)NBK * 4);
  int* bstart  = (int*)alloc((size_t)NBK * 4);
  float* fmax1 = (float*)alloc(32);
  float* va    = (float*)alloc(64);
  float* vd    = (float*)alloc(64);

  (void)hipMemsetAsync(maxenc, 0, 256, stream);

  k_xform1<<<XB + NSB, 256, 0, stream>>>(x, W1, as1w, ad1w, ei, bcnt,
                                         h1, as1, ad1, maxenc);
  k_rxScanB<<<NBK, 256, 0, stream>>>(bcnt, boffs, btot);
  k_rxTot<<<1, 256, 0, stream>>>(btot, bstart, start, maxenc, fmax1,
                                 W2, as2w, ad2w, va, vd);
  k_rxScat<<<NSB, 256, 0, stream>>>(ei, bstart, boffs, eb);
  k_rxB<<<NBK, 256, 0, stream>>>(eb, bstart, start, esrc);

  k_agg1<<<N_NODES / 16, 256, 0, stream>>>(h1, as1, ad1, start, esrc, b1,
                                           va, vd, fmax1, h1o, as2, ad2);
  k_maxas2<<<64, 256, 0, stream>>>(as2, maxenc + 8);
  k_agg2<<<(N_NODES + 3) / 4, 256, 0, stream>>>(h1o, as2, ad2, start, esrc, b2,
                                                W2, maxenc + 8, out);
}

// Round 22
// 151.037 us; speedup vs baseline: 1.2450x; 1.0060x over previous
//
#include <hip/hip_runtime.h>
#include <hip/hip_fp16.h>
#include <math.h>

#define N_NODES 50000
#define N_EDGES 1000000
#define F_IN 128
#define HID 16
#define N_CLS 40
#define HEADS 8
#define ET (N_EDGES + N_NODES)
#define XB ((N_NODES + 63) / 64)   // 782 xform blocks
#define NBK 196                    // coarse buckets (dst >> 8)
#define NSB 256                    // scatter blocks
#define ECH ((ET + NSB - 1) / NSB) // 4103 edges per scatter block

__device__ __forceinline__ void fma4(float4& acc, float s, const float4& v) {
  acc.x += s * v.x;
  acc.y += s * v.y;
  acc.z += s * v.z;
  acc.w += s * v.w;
}

__device__ __forceinline__ float dot4(float4 a, float4 b) {
  return a.x * b.x + a.y * b.y + a.z * b.z + a.w * b.w;
}

// monotone float<->uint encoding for atomicMax on floats
__device__ __forceinline__ unsigned encf(float f) {
  unsigned b = __float_as_uint(f);
  return (b & 0x80000000u) ? ~b : (b | 0x80000000u);
}
__device__ __forceinline__ float decf(unsigned k) {
  unsigned b = (k & 0x80000000u) ? (k ^ 0x80000000u) : ~k;
  return __uint_as_float(b);
}

// ---------------- conv1 transform (+ fused coarse-histogram blocks) ---------

__global__ __launch_bounds__(256, 4) void k_xform1(
    const float* __restrict__ x, const float* __restrict__ W1,
    const float* __restrict__ att_s, const float* __restrict__ att_d,
    const int* __restrict__ ei, int* __restrict__ bcnt,
    __half* __restrict__ h1, float* __restrict__ as1, float* __restrict__ ad1,
    unsigned* __restrict__ enc1) {
  __shared__ float4 xlds[64 * 9];   // [node][k-quad within phase], padded
  __shared__ float4 wlds[32 * 33];  // [k within phase][c-quad], padded
  __shared__ unsigned encl[8];
  int t = threadIdx.x;

  if (blockIdx.x >= XB) {  // coarse histogram blocks (reuse xlds as counters)
    int* cnt = (int*)xlds;
    int blk = blockIdx.x - XB;
    if (t < NBK) cnt[t] = 0;
    __syncthreads();
    int lo = blk * ECH + t;
    int hi = min((blk + 1) * ECH, ET);
    for (int i = lo; i < hi; i += 256) {
      int d = (i < N_EDGES) ? ei[N_EDGES + i] : (i - N_EDGES);
      atomicAdd(&cnt[d >> 8], 1);
    }
    __syncthreads();
    if (t < NBK) bcnt[t * NSB + blk] = cnt[t];
    return;
  }

  if (t < 8) encl[t] = 0u;
  int tx = t & 15, ty = t >> 4;
  int base = blockIdx.x * 64;
  const float4* x4 = (const float4*)x;
  const float4* W4 = (const float4*)W1;

  float4 accA[4], accB[4];
#pragma unroll
  for (int n = 0; n < 4; n++) {
    accA[n] = {0.f, 0.f, 0.f, 0.f};
    accB[n] = {0.f, 0.f, 0.f, 0.f};
  }
  int n0 = ty * 4;

  for (int kb = 0; kb < 4; kb++) {
    __syncthreads();
    {
      int i = t;
      int n = i >> 3, q = i & 7;
      int gn = base + n;
      float4 v = {0.f, 0.f, 0.f, 0.f};
      if (gn < N_NODES) v = x4[(size_t)gn * 32 + kb * 8 + q];
      xlds[n * 9 + q] = v;
      i += 256;
      n = i >> 3; q = i & 7;
      gn = base + n;
      float4 v2 = {0.f, 0.f, 0.f, 0.f};
      if (gn < N_NODES) v2 = x4[(size_t)gn * 32 + kb * 8 + q];
      xlds[n * 9 + q] = v2;
    }
#pragma unroll
    for (int u = 0; u < 4; u++) {
      int i = t + u * 256;
      int r = i >> 5, q = i & 31;
      wlds[r * 33 + q] = W4[(size_t)(kb * 32 + r) * 32 + q];
    }
    __syncthreads();
#pragma unroll
    for (int kk = 0; kk < 8; kk++) {
      float4 xv0 = xlds[(n0 + 0) * 9 + kk];
      float4 xv1 = xlds[(n0 + 1) * 9 + kk];
      float4 xv2 = xlds[(n0 + 2) * 9 + kk];
      float4 xv3 = xlds[(n0 + 3) * 9 + kk];
#pragma unroll
      for (int j = 0; j < 4; j++) {
        float4 wA = wlds[(kk * 4 + j) * 33 + tx];
        float4 wB = wlds[(kk * 4 + j) * 33 + tx + 16];
        float s0 = (j == 0) ? xv0.x : (j == 1) ? xv0.y : (j == 2) ? xv0.z : xv0.w;
        float s1 = (j == 0) ? xv1.x : (j == 1) ? xv1.y : (j == 2) ? xv1.z : xv1.w;
        float s2 = (j == 0) ? xv2.x : (j == 1) ? xv2.y : (j == 2) ? xv2.z : xv2.w;
        float s3 = (j == 0) ? xv3.x : (j == 1) ? xv3.y : (j == 2) ? xv3.z : xv3.w;
        fma4(accA[0], s0, wA); fma4(accB[0], s0, wB);
        fma4(accA[1], s1, wA); fma4(accB[1], s1, wB);
        fma4(accA[2], s2, wA); fma4(accB[2], s2, wB);
        fma4(accA[3], s3, wA); fma4(accB[3], s3, wB);
      }
    }
  }

  int c4 = tx * 4;
  float4 asA = *(const float4*)(att_s + c4);
  float4 asB = *(const float4*)(att_s + 64 + c4);
  float4 adA = *(const float4*)(att_d + c4);
  float4 adB = *(const float4*)(att_d + 64 + c4);
  float mxA = -1e30f, mxB = -1e30f;
#pragma unroll
  for (int n = 0; n < 4; n++) {
    int gn = base + n0 + n;
    float psA = dot4(accA[n], asA);
    float psB = dot4(accB[n], asB);
    float pdA = dot4(accA[n], adA);
    float pdB = dot4(accB[n], adB);
    psA += __shfl_xor(psA, 1); psA += __shfl_xor(psA, 2);
    psB += __shfl_xor(psB, 1); psB += __shfl_xor(psB, 2);
    pdA += __shfl_xor(pdA, 1); pdA += __shfl_xor(pdA, 2);
    pdB += __shfl_xor(pdB, 1); pdB += __shfl_xor(pdB, 2);
    if (gn < N_NODES) {
      uint2 pkA, pkB;
      __half2* phA = (__half2*)&pkA;
      __half2* phB = (__half2*)&pkB;
      phA[0] = __floats2half2_rn(accA[n].x, accA[n].y);
      phA[1] = __floats2half2_rn(accA[n].z, accA[n].w);
      phB[0] = __floats2half2_rn(accB[n].x, accB[n].y);
      phB[1] = __floats2half2_rn(accB[n].z, accB[n].w);
      *(uint2*)(h1 + (size_t)gn * 128 + c4) = pkA;
      *(uint2*)(h1 + (size_t)gn * 128 + 64 + c4) = pkB;
      mxA = fmaxf(mxA, psA);
      mxB = fmaxf(mxB, psB);
      if ((tx & 3) == 0) {
        as1[gn * 8 + (tx >> 2)] = psA;
        as1[gn * 8 + 4 + (tx >> 2)] = psB;
        ad1[gn * 8 + (tx >> 2)] = pdA;
        ad1[gn * 8 + 4 + (tx >> 2)] = pdB;
      }
    }
  }
  if ((tx & 3) == 0) {
    atomicMax(&encl[tx >> 2], encf(mxA));
    atomicMax(&encl[4 + (tx >> 2)], encf(mxB));
  }
  __syncthreads();
  if (t < 8) atomicMax(&enc1[t], encl[t]);
}

// ---------------- radix CSR build (packed edge records) ----------------

__global__ __launch_bounds__(256) void k_rxScanB(const int* __restrict__ bcnt,
                                                 int* __restrict__ boffs,
                                                 int* __restrict__ btot) {
  __shared__ int s[256];
  int b = blockIdx.x, t = threadIdx.x;
  int v0 = bcnt[b * NSB + t];
  s[t] = v0;
  __syncthreads();
  for (int off = 1; off < 256; off <<= 1) {
    int v = (t >= off) ? s[t - off] : 0;
    __syncthreads();
    s[t] += v;
    __syncthreads();
  }
  boffs[b * NSB + t] = s[t] - v0;
  if (t == 255) btot[b] = s[255];
}

// bucket-total scan + fmax decode + va/vd = W2-projected att vectors

__global__ __launch_bounds__(256) void k_rxTot(const int* __restrict__ btot,
                                               int* __restrict__ bstart,
                                               int* __restrict__ start,
                                               const unsigned* __restrict__ enc1,
                                               float* __restrict__ fmax1,
                                               const float* __restrict__ W2,
                                               const float* __restrict__ att_s2,
                                               const float* __restrict__ att_d2,
                                               float* __restrict__ va,
                                               float* __restrict__ vd) {
  __shared__ int s[256];
  int t = threadIdx.x;
  int v0 = (t < NBK) ? btot[t] : 0;
  s[t] = v0;
  __syncthreads();
  for (int off = 1; off < 256; off <<= 1) {
    int v = (t >= off) ? s[t - off] : 0;
    __syncthreads();
    s[t] += v;
    __syncthreads();
  }
  if (t < NBK) bstart[t] = s[t] - v0;
  if (t == 0) start[N_NODES] = ET;
  if (t < 8) fmax1[t] = decf(enc1[t]);
  if (t < 16) {
    float a = 0.f, dd = 0.f;
    for (int j = 0; j < N_CLS; j++) {
      float w = W2[t * N_CLS + j];
      a = fmaf(w, att_s2[j], a);
      dd = fmaf(w, att_d2[j], dd);
    }
    va[t] = a;
    vd[t] = dd;
  }
}

__global__ __launch_bounds__(256) void k_rxScat(const int* __restrict__ ei,
                                                const int* __restrict__ bstart,
                                                const int* __restrict__ boffs,
                                                int* __restrict__ eb) {
  __shared__ int cur[NBK];
  int t = threadIdx.x, blk = blockIdx.x;
  if (t < NBK) cur[t] = bstart[t] + boffs[t * NSB + blk];
  __syncthreads();
  int lo = blk * ECH + t;
  int hi = min((blk + 1) * ECH, ET);
  for (int i = lo; i < hi; i += 256) {
    int s, d;
    if (i < N_EDGES) { s = ei[i]; d = ei[N_EDGES + i]; }
    else { s = i - N_EDGES; d = s; }
    int pos = atomicAdd(&cur[d >> 8], 1);
    eb[pos] = s | ((d & 255) << 16);  // s < 65536
  }
}

__global__ __launch_bounds__(256) void k_rxB(const int* __restrict__ eb,
                                             const int* __restrict__ bstart,
                                             int* __restrict__ start,
                                             int* __restrict__ esrc) {
  __shared__ int dcnt[256], lst[256], ssc[256];
  __shared__ int esl[8192];  // bucket cap (mean 5357, +39 sigma)
  int t = threadIdx.x, b = blockIdx.x;
  int nlo = b * 256;
  int nn = min(256, N_NODES - nlo);
  int e0 = bstart[b];
  int e1 = (b == NBK - 1) ? ET : bstart[b + 1];
  int cnt = e1 - e0;
  dcnt[t] = 0;
  __syncthreads();
  for (int e = t; e < cnt; e += 256) atomicAdd(&dcnt[(eb[e0 + e] >> 16) & 255], 1);
  __syncthreads();
  int v0 = dcnt[t];
  ssc[t] = v0;
  __syncthreads();
  for (int off = 1; off < 256; off <<= 1) {
    int v = (t >= off) ? ssc[t - off] : 0;
    __syncthreads();
    ssc[t] += v;
    __syncthreads();
  }
  lst[t] = ssc[t] - v0;  // exclusive
  if (t < nn) start[nlo + t] = e0 + lst[t];
  dcnt[t] = lst[t];      // reuse as cursor
  __syncthreads();
  for (int e = t; e < cnt; e += 256) {
    int v = eb[e0 + e];
    int pos = atomicAdd(&dcnt[(v >> 16) & 255], 1);
    esl[pos] = v & 0xFFFF;
  }
  __syncthreads();
  for (int e = t; e < cnt; e += 256) esrc[e0 + e] = esl[e];
}

// ---------------- conv1 aggregation (1-wave blocks for max occupancy) -------
// Wave = 4 dst (16-lane groups); waves fully independent -> 64-thread blocks.

__global__ __launch_bounds__(64) void k_agg1(
    const __half* __restrict__ h1, const float* __restrict__ as1,
    const float* __restrict__ ad1, const int* __restrict__ start,
    const int* __restrict__ esrc, const float* __restrict__ b1,
    const float* __restrict__ va, const float* __restrict__ vd,
    const float* __restrict__ fmax1,
    __half* __restrict__ h1o, float* __restrict__ as2, float* __restrict__ ad2) {
  __shared__ __align__(16) __half2 p_t[4 * 164];  // [g*164 + head*20 + e]
  __shared__ __align__(16) int s_off[4][20];      // [g][16e+pad]
  int lane = threadIdx.x & 63;

  int g = lane >> 4, li = lane & 15;
  int d = blockIdx.x * 4 + g;  // 12500*4 = 50000 exact
  int s0 = start[d];
  int deg = start[d + 1] - s0;

  int dm = deg;
  dm = max(dm, __shfl_xor(dm, 16));
  dm = max(dm, __shfl_xor(dm, 32));

  float4 av0 = *(const float4*)(ad1 + d * 8);
  float4 av1 = *(const float4*)(ad1 + d * 8 + 4);
  float ad_[8] = {av0.x, av0.y, av0.z, av0.w, av1.x, av1.y, av1.z, av1.w};
  float c_[8];
#pragma unroll
  for (int h = 0; h < 8; h++) {
    float e = fmax1[h] + ad_[h];
    c_[h] = e > 0.f ? e : 0.2f * e;
  }

  float den = 0.f;
  float accf[8];
#pragma unroll
  for (int k = 0; k < 8; k++) accf[k] = 0.f;

  int hsel = li >> 1;
  const char* h1l = (const char*)(h1 + li * 8);  // lane's 16B channel chunk
  __half2* ptw = &p_t[g * 164];
  const int* so = &s_off[g][0];

  for (int be = 0; be < dm; be += 16) {
    int cnt = deg - be;  // may be <= 0
    bool act = li < cnt;
    int s = 0;
    if (act) s = esrc[s0 + be + li];
    s_off[g][li] = act ? (s << 8) : 0;
    float4 p0 = {0.f, 0.f, 0.f, 0.f}, p1 = {0.f, 0.f, 0.f, 0.f};
    if (act) {
      p0 = *(const float4*)(as1 + (size_t)s * 8);
      p1 = *(const float4*)(as1 + (size_t)s * 8 + 4);
    }
    float ev[8] = {p0.x, p0.y, p0.z, p0.w, p1.x, p1.y, p1.z, p1.w};
#pragma unroll
    for (int h = 0; h < 8; h++) {
      float v = ev[h] + ad_[h];
      v = v > 0.f ? v : 0.2f * v;
      float pv = act ? __expf(v - c_[h]) : 0.f;
      __half hp = __float2half(pv);
      ptw[h * 20 + li] = __half2{hp, hp};
    }
    asm volatile("s_waitcnt lgkmcnt(0)" ::: "memory");

    int cm = min(dm - be, 16);
    const __half2* pt = ptw + hsel * 20;
    __half2 a0 = __floats2half2_rn(0.f, 0.f);
    __half2 a1 = __floats2half2_rn(0.f, 0.f);
    __half2 a2 = __floats2half2_rn(0.f, 0.f);
    __half2 a3 = __floats2half2_rn(0.f, 0.f);
    for (int e = 0; e < cm; e += 8) {  // pad entries are (p=0, off=0): safe
      int4 s4 = *(const int4*)&so[e];
      int4 s8 = *(const int4*)&so[e + 4];
      uint4 pwA = *(const uint4*)&pt[e];
      uint4 pwB = *(const uint4*)&pt[e + 4];
      const __half2* ppA = (const __half2*)&pwA;
      const __half2* ppB = (const __half2*)&pwB;
      uint4 hA = *(const uint4*)(h1l + (unsigned)s4.x);
      uint4 hB = *(const uint4*)(h1l + (unsigned)s4.y);
      uint4 hC = *(const uint4*)(h1l + (unsigned)s4.z);
      uint4 hD = *(const uint4*)(h1l + (unsigned)s4.w);
      uint4 hE = *(const uint4*)(h1l + (unsigned)s8.x);
      uint4 hF = *(const uint4*)(h1l + (unsigned)s8.y);
      uint4 hG = *(const uint4*)(h1l + (unsigned)s8.z);
      uint4 hH = *(const uint4*)(h1l + (unsigned)s8.w);
      const __half2* vA = (const __half2*)&hA;
      const __half2* vB = (const __half2*)&hB;
      const __half2* vC = (const __half2*)&hC;
      const __half2* vD = (const __half2*)&hD;
      const __half2* vE = (const __half2*)&hE;
      const __half2* vF = (const __half2*)&hF;
      const __half2* vG = (const __half2*)&hG;
      const __half2* vH = (const __half2*)&hH;
      a0 = __hfma2(vA[0], ppA[0], a0); a1 = __hfma2(vA[1], ppA[0], a1);
      a2 = __hfma2(vA[2], ppA[0], a2); a3 = __hfma2(vA[3], ppA[0], a3);
      a0 = __hfma2(vB[0], ppA[1], a0); a1 = __hfma2(vB[1], ppA[1], a1);
      a2 = __hfma2(vB[2], ppA[1], a2); a3 = __hfma2(vB[3], ppA[1], a3);
      a0 = __hfma2(vC[0], ppA[2], a0); a1 = __hfma2(vC[1], ppA[2], a1);
      a2 = __hfma2(vC[2], ppA[2], a2); a3 = __hfma2(vC[3], ppA[2], a3);
      a0 = __hfma2(vD[0], ppA[3], a0); a1 = __hfma2(vD[1], ppA[3], a1);
      a2 = __hfma2(vD[2], ppA[3], a2); a3 = __hfma2(vD[3], ppA[3], a3);
      a0 = __hfma2(vE[0], ppB[0], a0); a1 = __hfma2(vE[1], ppB[0], a1);
      a2 = __hfma2(vE[2], ppB[0], a2); a3 = __hfma2(vE[3], ppB[0], a3);
      a0 = __hfma2(vF[0], ppB[1], a0); a1 = __hfma2(vF[1], ppB[1], a1);
      a2 = __hfma2(vF[2], ppB[1], a2); a3 = __hfma2(vF[3], ppB[1], a3);
      a0 = __hfma2(vG[0], ppB[2], a0); a1 = __hfma2(vG[1], ppB[2], a1);
      a2 = __hfma2(vG[2], ppB[2], a2); a3 = __hfma2(vG[3], ppB[2], a3);
      a0 = __hfma2(vH[0], ppB[3], a0); a1 = __hfma2(vH[1], ppB[3], a1);
      a2 = __hfma2(vH[2], ppB[3], a2); a3 = __hfma2(vH[3], ppB[3], a3);
      den += __low2float(ppA[0]) + __low2float(ppA[1]) +
             __low2float(ppA[2]) + __low2float(ppA[3]) +
             __low2float(ppB[0]) + __low2float(ppB[1]) +
             __low2float(ppB[2]) + __low2float(ppB[3]);
    }
    // promote chunk accumulators to fp32
    float2 f0 = __half22float2(a0), f1 = __half22float2(a1);
    float2 f2 = __half22float2(a2), f3 = __half22float2(a3);
    accf[0] += f0.x; accf[1] += f0.y; accf[2] += f1.x; accf[3] += f1.y;
    accf[4] += f2.x; accf[5] += f2.y; accf[6] += f3.x; accf[7] += f3.y;
    asm volatile("s_waitcnt lgkmcnt(0)" ::: "memory");
  }

  // normalize by own head's den, fold in 1/8 head-mean
  float sc = 0.125f / den;
#pragma unroll
  for (int k = 0; k < 8; k++) accf[k] *= sc;
  // sum over heads: xor 2,4,8 within the 16-lane group
#pragma unroll
  for (int off = 2; off <= 8; off <<= 1) {
#pragma unroll
    for (int k = 0; k < 8; k++) accf[k] += __shfl_xor(accf[k], off);
  }
  // lane holds mean for ch (li&1)*8 + k
  int jb = (li & 1) * 8;
  float4 b1a = *(const float4*)(b1 + jb);
  float4 b1b = *(const float4*)(b1 + jb + 4);
  float bv[8] = {b1a.x, b1a.y, b1a.z, b1a.w, b1b.x, b1b.y, b1b.z, b1b.w};
  float r[8];
#pragma unroll
  for (int k = 0; k < 8; k++) {
    float v = accf[k] + bv[k];
    r[k] = v > 0.f ? v : __expf(v) - 1.f;
  }

  // store h1out (li=0: ch0-7, li=1: ch8-15) as one uint4 each
  if (li < 2) {
    uint4 pk;
    __half2* ph = (__half2*)&pk;
    ph[0] = __floats2half2_rn(r[0], r[1]);
    ph[1] = __floats2half2_rn(r[2], r[3]);
    ph[2] = __floats2half2_rn(r[4], r[5]);
    ph[3] = __floats2half2_rn(r[6], r[7]);
    *(uint4*)(h1o + (size_t)d * 16 + li * 8) = pk;
  }
  // as2/ad2 via projected att vectors
  float4 vaA = *(const float4*)(va + jb);
  float4 vaB = *(const float4*)(va + jb + 4);
  float4 vdA = *(const float4*)(vd + jb);
  float4 vdB = *(const float4*)(vd + jb + 4);
  float sv = r[0] * vaA.x + r[1] * vaA.y + r[2] * vaA.z + r[3] * vaA.w +
             r[4] * vaB.x + r[5] * vaB.y + r[6] * vaB.z + r[7] * vaB.w;
  float dv = r[0] * vdA.x + r[1] * vdA.y + r[2] * vdA.z + r[3] * vdA.w +
             r[4] * vdB.x + r[5] * vdB.y + r[6] * vdB.z + r[7] * vdB.w;
  sv += __shfl_xor(sv, 1);
  dv += __shfl_xor(dv, 1);
  if (li == 0) { as2[d] = sv; ad2[d] = dv; }
}

// ---------------- global max of as2 ----------------

__global__ __launch_bounds__(256) void k_maxas2(const float* __restrict__ as2,
                                                unsigned* __restrict__ enc) {
  int t = blockIdx.x * 256 + threadIdx.x;  // 64 blocks -> 16384 threads
  float mx = -1e30f;
  for (int r = t; r < N_NODES; r += 16384) mx = fmaxf(mx, as2[r]);
#pragma unroll
  for (int off = 32; off; off >>= 1) mx = fmaxf(mx, __shfl_xor(mx, off));
  if ((threadIdx.x & 63) == 0) atomicMax(enc, encf(mx));
}

// ---------------- conv2 aggregation: gather h1out (32B/edge), W2 at end -----

__global__ __launch_bounds__(256) void k_agg2(
    const __half* __restrict__ h1o, const float* __restrict__ as2,
    const float* __restrict__ ad2, const int* __restrict__ start,
    const int* __restrict__ esrc, const float* __restrict__ b2,
    const float* __restrict__ W2, const unsigned* __restrict__ as2maxEnc,
    float* __restrict__ out) {
  __shared__ __align__(16) float p_l[4][64];
  __shared__ __align__(16) int s_l[4][64];  // byte offsets (s*32)
  __shared__ float w2s[16 * 40];
  int t = threadIdx.x;
  for (int i = t; i < 640; i += 256) w2s[i] = W2[i];
  __syncthreads();

  int wave = t >> 6, lane = t & 63;
  int d = blockIdx.x * 4 + wave;
  if (d >= N_NODES) return;
  int s0 = start[d];
  int deg = start[d + 1] - s0;
  float adv = ad2[d];
  float cm = decf(as2maxEnc[0]) + adv;
  cm = cm > 0.f ? cm : 0.2f * cm;

  int cp = lane & 7;   // channel pair (ch 2cp, 2cp+1)
  int es = lane >> 3;  // edge slot 0..7
  const char* hb = (const char*)h1o + cp * 4;

  float den = 0.f, acc0 = 0.f, acc1 = 0.f;
  for (int be = 0; be < deg; be += 64) {
    int cnt = min(64, deg - be);
    if (lane < cnt) {
      int s = esrc[s0 + be + lane];
      s_l[wave][lane] = s * 32;  // byte offset into h1o (16 halves)
      float e = as2[s] + adv;
      e = e > 0.f ? e : 0.2f * e;
      float p = __expf(e - cm);
      den += p;
      p_l[wave][lane] = p;
    }
    asm volatile("s_waitcnt lgkmcnt(0)" ::: "memory");
    int i = es;
    for (; i + 8 < cnt; i += 16) {
      int sbA = s_l[wave][i], sbB = s_l[wave][i + 8];
      float pA = p_l[wave][i], pB = p_l[wave][i + 8];
      __half2 hvA = *(const __half2*)(hb + (unsigned)sbA);
      __half2 hvB = *(const __half2*)(hb + (unsigned)sbB);
      acc0 = fmaf(__half2float(hvA.x), pA, acc0);
      acc1 = fmaf(__half2float(hvA.y), pA, acc1);
      acc0 = fmaf(__half2float(hvB.x), pB, acc0);
      acc1 = fmaf(__half2float(hvB.y), pB, acc1);
    }
    if (i < cnt) {
      int sb = s_l[wave][i];
      float p = p_l[wave][i];
      __half2 hv = *(const __half2*)(hb + (unsigned)sb);
      acc0 = fmaf(__half2float(hv.x), p, acc0);
      acc1 = fmaf(__half2float(hv.y), p, acc1);
    }
    asm volatile("s_waitcnt lgkmcnt(0)" ::: "memory");
  }
#pragma unroll
  for (int off = 32; off; off >>= 1) den += __shfl_xor(den, off);
  float iv = 1.f / den;

  // combine 8 edge-slots (lanes sharing cp): xor 8,16,32
  acc0 += __shfl_xor(acc0, 8);  acc1 += __shfl_xor(acc1, 8);
  acc0 += __shfl_xor(acc0, 16); acc1 += __shfl_xor(acc1, 16);
  acc0 += __shfl_xor(acc0, 32); acc1 += __shfl_xor(acc1, 32);
  float m0 = acc0 * iv, m1 = acc1 * iv;

  // matvec: out_j = sum_k m_k W2[k][j] + b2[j], j = lane < 40
  float v = 0.f;
#pragma unroll
  for (int k = 0; k < 16; k++) {
    float ms = (k & 1) ? m1 : m0;
    float mk = __shfl(ms, k >> 1);
    if (lane < N_CLS) v = fmaf(mk, w2s[k * 40 + lane], v);
  }
  v = (lane < N_CLS) ? v + b2[lane] : -1e30f;

  float mx = v;
#pragma unroll
  for (int off = 32; off; off >>= 1) mx = fmaxf(mx, __shfl_xor(mx, off));
  float ex = (lane < N_CLS) ? __expf(v - mx) : 0.f;
  float sm = ex;
#pragma unroll
  for (int off = 32; off; off >>= 1) sm += __shfl_xor(sm, off);
  float lse = logf(sm);
  if (lane < N_CLS) out[d * N_CLS + lane] = (v - mx) - lse;
}

// ---------------- host launcher ----------------

extern "C" void kernel_launch(void* const* d_in, const int* in_sizes, int n_in,
                              void* d_out, int out_size, void* d_ws, size_t ws_size,
                              hipStream_t stream) {
  const float* x    = (const float*)d_in[0];
  const int*   ei   = (const int*)d_in[1];
  const float* W1   = (const float*)d_in[2];
  const float* as1w = (const float*)d_in[3];
  const float* ad1w = (const float*)d_in[4];
  const float* b1   = (const float*)d_in[5];
  const float* W2   = (const float*)d_in[6];
  const float* as2w = (const float*)d_in[7];
  const float* ad2w = (const float*)d_in[8];
  const float* b2   = (const float*)d_in[9];
  float* out = (float*)d_out;

  char* ws = (char*)d_ws;
  size_t off = 0;
  auto alloc = [&](size_t bytes) -> void* {
    void* p = ws + off;
    off += (bytes + 255) & ~(size_t)255;
    return p;
  };
  __half* h1   = (__half*)alloc((size_t)N_NODES * 128 * 2);
  float* as1   = (float*)alloc((size_t)N_NODES * 8 * 4);
  float* ad1   = (float*)alloc((size_t)N_NODES * 8 * 4);
  __half* h1o  = (__half*)alloc((size_t)N_NODES * 16 * 2);
  float* as2   = (float*)alloc((size_t)N_NODES * 4);
  float* ad2   = (float*)alloc((size_t)N_NODES * 4);
  unsigned* maxenc = (unsigned*)alloc(256);  // [0..7]=as1 heads, [8]=as2
  int* start   = (int*)alloc((size_t)(N_NODES + 1) * 4);
  int* esrc    = (int*)alloc((size_t)ET * 4);
  int* eb      = (int*)alloc((size_t)ET * 4);
  int* bcnt    = (int*)alloc((size_t)NBK * NSB * 4);
  int* boffs   = (int*)alloc((size_t)NBK * NSB * 4);
  int* btot    = (int*)alloc((size_t)NBK * 4);
  int* bstart  = (int*)alloc((size_t)NBK * 4);
  float* fmax1 = (float*)alloc(32);
  float* va    = (float*)alloc(64);
  float* vd    = (float*)alloc(64);

  (void)hipMemsetAsync(maxenc, 0, 256, stream);

  k_xform1<<<XB + NSB, 256, 0, stream>>>(x, W1, as1w, ad1w, ei, bcnt,
                                         h1, as1, ad1, maxenc);
  k_rxScanB<<<NBK, 256, 0, stream>>>(bcnt, boffs, btot);
  k_rxTot<<<1, 256, 0, stream>>>(btot, bstart, start, maxenc, fmax1,
                                 W2, as2w, ad2w, va, vd);
  k_rxScat<<<NSB, 256, 0, stream>>>(ei, bstart, boffs, eb);
  k_rxB<<<NBK, 256, 0, stream>>>(eb, bstart, start, esrc);

  k_agg1<<<N_NODES / 4, 64, 0, stream>>>(h1, as1, ad1, start, esrc, b1,
                                         va, vd, fmax1, h1o, as2, ad2);
  k_maxas2<<<64, 256, 0, stream>>>(as2, maxenc + 8);
  k_agg2<<<(N_NODES + 3) / 4, 256, 0, stream>>>(h1o, as2, ad2, start, esrc, b2,
                                                W2, maxenc + 8, out);
}